// Round 1
// baseline (1044.198 us; speedup 1.0000x reference)
//
#include <hip/hip_runtime.h>
#include <hip/hip_bf16.h>
#include <stdint.h>

// ---------------- types ----------------
typedef __bf16 bf16_t;
typedef bf16_t bf16x8 __attribute__((ext_vector_type(8)));
typedef bf16_t bf16x4v __attribute__((ext_vector_type(4)));
typedef float  f32x4  __attribute__((ext_vector_type(4)));

#define D_MODEL 1024
#define D_STATE 128
#define D_INNER 2048
#define HEADS   1024
#define PROJ    5376
#define LSEQ    2048
#define BATCH   2
#define NROW    (BATCH*LSEQ)   // 4096

// offsets within a zxbcdt row: x[0:2048] z[2048:4096] B[4096:4224] C[4224:4352] dt[4352:5376]
#define OFF_X   0
#define OFF_Z   2048
#define OFF_B   4096
#define OFF_C   4224
#define OFF_DT  4352

typedef __attribute__((address_space(1))) void void_as1;
typedef __attribute__((address_space(3))) void void_as3;

__device__ __forceinline__ void gload_lds16(const void* g, void* l) {
  // direct global->LDS DMA, 16B per lane; LDS dest must be wave-uniform base + lane*16
  __builtin_amdgcn_global_load_lds((void_as1*)(uintptr_t)g,
                                   (void_as3*)(uint32_t)(uintptr_t)l,
                                   16, 0, 0);
}

__device__ __forceinline__ float siluf(float v) { return v / (1.f + expf(-v)); }

// ---------------- transpose fp32 (R x C) -> bf16 (C x R) ----------------
__global__ __launch_bounds__(256) void transpose_kernel(const float* __restrict__ src,
                                                        bf16_t* __restrict__ dst,
                                                        int R, int C) {
  __shared__ float tile[32][33];
  int c0 = blockIdx.x * 32, r0 = blockIdx.y * 32;
  int tx = threadIdx.x, ty = threadIdx.y;
  #pragma unroll
  for (int i = ty; i < 32; i += 8)
    tile[i][tx] = src[(size_t)(r0 + i) * C + c0 + tx];
  __syncthreads();
  #pragma unroll
  for (int i = ty; i < 32; i += 8)
    dst[(size_t)(c0 + i) * R + r0 + tx] = (bf16_t)tile[tx][i];
}

// ---------------- layernorm -> bf16 ----------------
__global__ __launch_bounds__(256) void ln_kernel(const float* __restrict__ u,
                                                 const float* __restrict__ g,
                                                 const float* __restrict__ bb,
                                                 bf16_t* __restrict__ xn) {
  int row = blockIdx.x;                       // 4096 rows
  int t = threadIdx.x;
  float4 v = ((const float4*)(u + (size_t)row * D_MODEL))[t];
  float s  = v.x + v.y + v.z + v.w;
  float s2 = v.x*v.x + v.y*v.y + v.z*v.z + v.w*v.w;
  #pragma unroll
  for (int m = 1; m < 64; m <<= 1) { s += __shfl_xor(s, m, 64); s2 += __shfl_xor(s2, m, 64); }
  __shared__ float ws[8];
  int wv = t >> 6, lane = t & 63;
  if (lane == 0) { ws[wv] = s; ws[4 + wv] = s2; }
  __syncthreads();
  s  = ws[0] + ws[1] + ws[2] + ws[3];
  s2 = ws[4] + ws[5] + ws[6] + ws[7];
  float mean = s * (1.f / D_MODEL);
  float var  = s2 * (1.f / D_MODEL) - mean * mean;
  float rstd = rsqrtf(var + 1e-5f);
  float4 gv = ((const float4*)g)[t];
  float4 bv = ((const float4*)bb)[t];
  bf16x4v o;
  o[0] = (bf16_t)((v.x - mean) * rstd * gv.x + bv.x);
  o[1] = (bf16_t)((v.y - mean) * rstd * gv.y + bv.y);
  o[2] = (bf16_t)((v.z - mean) * rstd * gv.z + bv.z);
  o[3] = (bf16_t)((v.w - mean) * rstd * gv.w + bv.w);
  *(bf16x4v*)(xn + (size_t)row * D_MODEL + t * 4) = o;
}

// ---------------- GEMM  C[M,N] = A[M,K] * BT[N,K]^T  (+optional resid) ----------------
// 128x128 tile, 4 waves (2x2 of 64x64), mfma_f32_16x16x32_bf16, BK=32
__global__ __launch_bounds__(256) void gemm_bt(const bf16_t* __restrict__ A,
                                               const bf16_t* __restrict__ BT,
                                               float* __restrict__ C,
                                               int M, int N, int K,
                                               const float* __restrict__ resid) {
  __shared__ bf16_t lA[128 * 32];
  __shared__ bf16_t lB[128 * 32];
  int ntile = N >> 7;
  int tm = blockIdx.x / ntile, tn = blockIdx.x % ntile;
  int m0 = tm << 7, n0 = tn << 7;
  int t = threadIdx.x;
  int wv = t >> 6, lane = t & 63;
  int wm = (wv >> 1) << 6, wn = (wv & 1) << 6;
  int l15 = lane & 15, l4 = lane >> 4;

  f32x4 acc[4][4];
  #pragma unroll
  for (int i = 0; i < 4; ++i)
    #pragma unroll
    for (int j = 0; j < 4; ++j) acc[i][j] = (f32x4){0.f, 0.f, 0.f, 0.f};

  int sr = t >> 2;                    // staging row 0..63
  int sk = (t & 3) * 8;               // staging k-offset
  const bf16_t* ga  = A  + (size_t)(m0 + sr) * K + sk;
  const bf16_t* ga2 = ga + (size_t)64 * K;
  const bf16_t* gb  = BT + (size_t)(n0 + sr) * K + sk;
  const bf16_t* gb2 = gb + (size_t)64 * K;
  bf16_t* la  = lA + t * 8;           // byte offset = t*16 (linear per lane)
  bf16_t* la2 = la + 2048;
  bf16_t* lb  = lB + t * 8;
  bf16_t* lb2 = lb + 2048;

  const bf16_t* raBase = lA + (wm + l15) * 32 + l4 * 8;
  const bf16_t* rbBase = lB + (wn + l15) * 32 + l4 * 8;

  for (int k0 = 0; k0 < K; k0 += 32) {
    gload_lds16(ga, la);  gload_lds16(ga2, la2);
    gload_lds16(gb, lb);  gload_lds16(gb2, lb2);
    ga += 32; ga2 += 32; gb += 32; gb2 += 32;
    __syncthreads();
    bf16x8 af[4], bq[4];
    #pragma unroll
    for (int f = 0; f < 4; ++f) {
      af[f] = *(const bf16x8*)(raBase + f * 512);
      bq[f] = *(const bf16x8*)(rbBase + f * 512);
    }
    #pragma unroll
    for (int i = 0; i < 4; ++i)
      #pragma unroll
      for (int j = 0; j < 4; ++j)
        acc[i][j] = __builtin_amdgcn_mfma_f32_16x16x32_bf16(af[i], bq[j], acc[i][j], 0, 0, 0);
    __syncthreads();
  }

  #pragma unroll
  for (int i = 0; i < 4; ++i) {
    int row = m0 + wm + i * 16 + l4 * 4;
    #pragma unroll
    for (int j = 0; j < 4; ++j) {
      int col = n0 + wn + j * 16 + l15;
      #pragma unroll
      for (int r = 0; r < 4; ++r) {
        size_t idx = (size_t)(row + r) * N + col;
        float v = acc[i][j][r];
        if (resid) v += resid[idx];
        C[idx] = v;
      }
    }
  }
}

// ---------------- prep: softplus(dt), decay, conv4+silu, dtx ----------------
__global__ __launch_bounds__(256) void prep_kernel(const float* __restrict__ zx,
                                                   const float* __restrict__ conv_w,
                                                   const float* __restrict__ conv_b,
                                                   const float* __restrict__ A_log,
                                                   float* __restrict__ decay,
                                                   float* __restrict__ dtx) {
  int idx = blockIdx.x * 256 + threadIdx.x;     // (b,t,h) linear over 4096*1024
  int h  = idx & (HEADS - 1);
  int bt = idx >> 10;
  int t  = bt & (LSEQ - 1);
  const float* row = zx + (size_t)bt * PROJ;
  float draw = row[OFF_DT + h];
  float dt = (draw > 20.f) ? draw : log1pf(expf(draw));
  float Ah = -expf(A_log[h]);
  decay[idx] = expf(dt * Ah);
  float4 w0 = *(const float4*)(conv_w + 8 * h);
  float4 w1 = *(const float4*)(conv_w + 8 * h + 4);
  float2 cb = *(const float2*)(conv_b + 2 * h);
  float acc0 = cb.x, acc1 = cb.y;
  float w0a[4] = {w0.x, w0.y, w0.z, w0.w};
  float w1a[4] = {w1.x, w1.y, w1.z, w1.w};
  #pragma unroll
  for (int k = 0; k < 4; ++k) {
    int tt = t - 3 + k;
    if (tt >= 0) {
      float2 xv = *(const float2*)(zx + (size_t)(bt - 3 + k) * PROJ + OFF_X + 2 * h);
      acc0 = fmaf(xv.x, w0a[k], acc0);
      acc1 = fmaf(xv.y, w1a[k], acc1);
    }
  }
  float xs0 = siluf(acc0), xs1 = siluf(acc1);
  *(float2*)(dtx + 2 * (size_t)idx) = make_float2(dt * xs0, dt * xs1);
}

// ---------------- selective scan: 2 heads per wave ----------------
// lane<32 -> head h0, lane>=32 -> head h0+1; each lane owns 4 states (float4 of n)
__global__ __launch_bounds__(256) void scan_kernel(const float* __restrict__ zx,
                                                   const float* __restrict__ dec,
                                                   const float* __restrict__ dtx,
                                                   float* __restrict__ y) {
  int gw   = (blockIdx.x * 256 + threadIdx.x) >> 6;  // wave 0..1023
  int lane = threadIdx.x & 63;
  int b  = gw >> 9;
  int h  = ((gw & 511) << 1) + (lane >> 5);
  int nl = (lane & 31) << 2;                         // n base
  const float* bcbase = zx + (size_t)b * LSEQ * PROJ;
  size_t idx = ((size_t)b * LSEQ) * HEADS + h;
  float h00=0,h01=0,h02=0,h03=0,h10=0,h11=0,h12=0,h13=0;

  float4 Bv = *(const float4*)(bcbase + OFF_B + nl);
  float4 Cv = *(const float4*)(bcbase + OFF_C + nl);
  float  dv = dec[idx];
  float2 xv = *(const float2*)(dtx + 2 * idx);

  for (int t = 0; t < LSEQ; ++t) {
    int tn = (t + 1 < LSEQ) ? (t + 1) : t;
    const float* rown = bcbase + (size_t)tn * PROJ;
    size_t idxn = ((size_t)b * LSEQ + tn) * HEADS + h;
    float4 Bn = *(const float4*)(rown + OFF_B + nl);
    float4 Cn = *(const float4*)(rown + OFF_C + nl);
    float  dn = dec[idxn];
    float2 xn2 = *(const float2*)(dtx + 2 * idxn);

    h00 = fmaf(dv, h00, xv.x * Bv.x); h01 = fmaf(dv, h01, xv.x * Bv.y);
    h02 = fmaf(dv, h02, xv.x * Bv.z); h03 = fmaf(dv, h03, xv.x * Bv.w);
    h10 = fmaf(dv, h10, xv.y * Bv.x); h11 = fmaf(dv, h11, xv.y * Bv.y);
    h12 = fmaf(dv, h12, xv.y * Bv.z); h13 = fmaf(dv, h13, xv.y * Bv.w);

    float y0 = h00 * Cv.x + h01 * Cv.y + h02 * Cv.z + h03 * Cv.w;
    float y1 = h10 * Cv.x + h11 * Cv.y + h12 * Cv.z + h13 * Cv.w;
    #pragma unroll
    for (int m = 16; m; m >>= 1) { y0 += __shfl_xor(y0, m, 64); y1 += __shfl_xor(y1, m, 64); }
    if ((lane & 31) == 0) *(float2*)(y + 2 * idx) = make_float2(y0, y1);

    idx += HEADS;
    Bv = Bn; Cv = Cn; dv = dn; xv = xn2;
  }
}

// ---------------- gate: yg = y * silu(z) -> bf16 ----------------
__global__ __launch_bounds__(256) void gate_kernel(const float* __restrict__ y,
                                                   const float* __restrict__ zx,
                                                   bf16_t* __restrict__ yg) {
  int tid = blockIdx.x * 256 + threadIdx.x;       // x4 elements
  int row = tid >> 9;
  int c0  = (tid & 511) * 4;
  float4 yv = *(const float4*)(y  + (size_t)row * D_INNER + c0);
  float4 zv = *(const float4*)(zx + (size_t)row * PROJ + OFF_Z + c0);
  bf16x4v o;
  o[0] = (bf16_t)(yv.x * siluf(zv.x));
  o[1] = (bf16_t)(yv.y * siluf(zv.y));
  o[2] = (bf16_t)(yv.z * siluf(zv.z));
  o[3] = (bf16_t)(yv.w * siluf(zv.w));
  *(bf16x4v*)(yg + (size_t)row * D_INNER + c0) = o;
}

// ---------------- launch ----------------
extern "C" void kernel_launch(void* const* d_in, const int* in_sizes, int n_in,
                              void* d_out, int out_size, void* d_ws, size_t ws_size,
                              hipStream_t stream) {
  const float* u      = (const float*)d_in[0];
  const float* W_in   = (const float*)d_in[1];
  const float* conv_w = (const float*)d_in[2];
  const float* conv_b = (const float*)d_in[3];
  const float* W_out  = (const float*)d_in[4];
  const float* ln_g   = (const float*)d_in[5];
  const float* ln_b   = (const float*)d_in[6];
  const float* A_log  = (const float*)d_in[7];
  float* out = (float*)d_out;

  // workspace carve-up (~203 MB total)
  char* ws = (char*)d_ws;
  bf16_t* W_inT  = (bf16_t*)ws;  ws += (size_t)PROJ * D_MODEL * 2;      // 11.0 MB
  bf16_t* W_outT = (bf16_t*)ws;  ws += (size_t)D_MODEL * D_INNER * 2;   //  4.2 MB
  bf16_t* xn     = (bf16_t*)ws;  ws += (size_t)NROW * D_MODEL * 2;      //  8.4 MB
  float*  zx     = (float*)ws;   ws += (size_t)NROW * PROJ * 4;         // 88.1 MB
  float*  dec    = (float*)ws;   ws += (size_t)NROW * HEADS * 4;        // 16.8 MB
  float*  dtx    = (float*)ws;   ws += (size_t)NROW * D_INNER * 4;      // 33.6 MB
  float*  yy     = (float*)ws;   ws += (size_t)NROW * D_INNER * 4;      // 33.6 MB
  bf16_t* yg     = (bf16_t*)ws;  ws += (size_t)NROW * D_INNER * 2;      // 16.8 MB

  dim3 tb(32, 8);
  transpose_kernel<<<dim3(PROJ / 32, D_MODEL / 32), tb, 0, stream>>>(W_in, W_inT, D_MODEL, PROJ);
  transpose_kernel<<<dim3(D_MODEL / 32, D_INNER / 32), tb, 0, stream>>>(W_out, W_outT, D_INNER, D_MODEL);
  ln_kernel<<<NROW, 256, 0, stream>>>(u, ln_g, ln_b, xn);
  gemm_bt<<<(NROW / 128) * (PROJ / 128), 256, 0, stream>>>(xn, W_inT, zx, NROW, PROJ, D_MODEL, nullptr);
  prep_kernel<<<NROW * HEADS / 256, 256, 0, stream>>>(zx, conv_w, conv_b, A_log, dec, dtx);
  scan_kernel<<<BATCH * HEADS / 2 / 4, 256, 0, stream>>>(zx, dec, dtx, yy);
  gate_kernel<<<NROW * D_INNER / 4 / 256, 256, 0, stream>>>(yy, zx, yg);
  gemm_bt<<<(NROW / 128) * (D_MODEL / 128), 256, 0, stream>>>(yg, W_outT, out, NROW, D_MODEL, D_INNER, u);
}

// Round 3
// 663.875 us; speedup vs baseline: 1.5729x; 1.5729x over previous
//
#include <hip/hip_runtime.h>
#include <hip/hip_bf16.h>
#include <stdint.h>

// ---------------- types ----------------
typedef __bf16 bf16_t;
typedef bf16_t bf16x8 __attribute__((ext_vector_type(8)));
typedef bf16_t bf16x4v __attribute__((ext_vector_type(4)));
typedef float  f32x4  __attribute__((ext_vector_type(4)));

#define D_MODEL 1024
#define D_STATE 128
#define D_INNER 2048
#define HEADS   1024
#define PROJ    5376
#define LSEQ    2048
#define BATCH   2
#define NROW    (BATCH*LSEQ)   // 4096

// offsets within a zxbcdt row: x[0:2048] z[2048:4096] B[4096:4224] C[4224:4352] dt[4352:5376]
#define OFF_X   0
#define OFF_Z   2048
#define OFF_B   4096
#define OFF_C   4224
#define OFF_DT  4352

typedef __attribute__((address_space(1))) void void_as1;
typedef __attribute__((address_space(3))) void void_as3;

__device__ __forceinline__ void gload_lds16(const void* g, void* l) {
  __builtin_amdgcn_global_load_lds((void_as1*)(uintptr_t)g,
                                   (void_as3*)(uint32_t)(uintptr_t)l,
                                   16, 0, 0);
}

__device__ __forceinline__ float siluf(float v) { return v / (1.f + expf(-v)); }

// DPP add-reduce helper: x += dpp_moved(x); CTRL/RM are compile-time constants.
template<int CTRL, int RM>
__device__ __forceinline__ float dpp_add(float x) {
  int s = __builtin_amdgcn_update_dpp(0, __float_as_int(x), CTRL, RM, 0xf, true);
  return x + __int_as_float(s);
}

// ---------------- transpose fp32 (R x C) -> bf16 (C x R) ----------------
__global__ __launch_bounds__(256) void transpose_kernel(const float* __restrict__ src,
                                                        bf16_t* __restrict__ dst,
                                                        int R, int C) {
  __shared__ float tile[32][33];
  int c0 = blockIdx.x * 32, r0 = blockIdx.y * 32;
  int tx = threadIdx.x, ty = threadIdx.y;
  #pragma unroll
  for (int i = ty; i < 32; i += 8)
    tile[i][tx] = src[(size_t)(r0 + i) * C + c0 + tx];
  __syncthreads();
  #pragma unroll
  for (int i = ty; i < 32; i += 8)
    dst[(size_t)(c0 + i) * R + r0 + tx] = (bf16_t)tile[tx][i];
}

// ---------------- layernorm -> bf16 ----------------
__global__ __launch_bounds__(256) void ln_kernel(const float* __restrict__ u,
                                                 const float* __restrict__ g,
                                                 const float* __restrict__ bb,
                                                 bf16_t* __restrict__ xn) {
  int row = blockIdx.x;                       // 4096 rows
  int t = threadIdx.x;
  float4 v = ((const float4*)(u + (size_t)row * D_MODEL))[t];
  float s  = v.x + v.y + v.z + v.w;
  float s2 = v.x*v.x + v.y*v.y + v.z*v.z + v.w*v.w;
  #pragma unroll
  for (int m = 1; m < 64; m <<= 1) { s += __shfl_xor(s, m, 64); s2 += __shfl_xor(s2, m, 64); }
  __shared__ float ws[8];
  int wv = t >> 6, lane = t & 63;
  if (lane == 0) { ws[wv] = s; ws[4 + wv] = s2; }
  __syncthreads();
  s  = ws[0] + ws[1] + ws[2] + ws[3];
  s2 = ws[4] + ws[5] + ws[6] + ws[7];
  float mean = s * (1.f / D_MODEL);
  float var  = s2 * (1.f / D_MODEL) - mean * mean;
  float rstd = rsqrtf(var + 1e-5f);
  float4 gv = ((const float4*)g)[t];
  float4 bv = ((const float4*)bb)[t];
  bf16x4v o;
  o[0] = (bf16_t)((v.x - mean) * rstd * gv.x + bv.x);
  o[1] = (bf16_t)((v.y - mean) * rstd * gv.y + bv.y);
  o[2] = (bf16_t)((v.z - mean) * rstd * gv.z + bv.z);
  o[3] = (bf16_t)((v.w - mean) * rstd * gv.w + bv.w);
  *(bf16x4v*)(xn + (size_t)row * D_MODEL + t * 4) = o;
}

// ---------------- GEMM  C[M,N] = A[M,K] * BT[N,K]^T  (+optional resid) ----------------
__global__ __launch_bounds__(256) void gemm_bt(const bf16_t* __restrict__ A,
                                               const bf16_t* __restrict__ BT,
                                               float* __restrict__ C,
                                               int M, int N, int K,
                                               const float* __restrict__ resid) {
  __shared__ bf16_t lA[128 * 32];
  __shared__ bf16_t lB[128 * 32];
  int ntile = N >> 7;
  int tm = blockIdx.x / ntile, tn = blockIdx.x % ntile;
  int m0 = tm << 7, n0 = tn << 7;
  int t = threadIdx.x;
  int wv = t >> 6, lane = t & 63;
  int wm = (wv >> 1) << 6, wn = (wv & 1) << 6;
  int l15 = lane & 15, l4 = lane >> 4;

  f32x4 acc[4][4];
  #pragma unroll
  for (int i = 0; i < 4; ++i)
    #pragma unroll
    for (int j = 0; j < 4; ++j) acc[i][j] = (f32x4){0.f, 0.f, 0.f, 0.f};

  int sr = t >> 2;
  int sk = (t & 3) * 8;
  const bf16_t* ga  = A  + (size_t)(m0 + sr) * K + sk;
  const bf16_t* ga2 = ga + (size_t)64 * K;
  const bf16_t* gb  = BT + (size_t)(n0 + sr) * K + sk;
  const bf16_t* gb2 = gb + (size_t)64 * K;
  bf16_t* la  = lA + t * 8;
  bf16_t* la2 = la + 2048;
  bf16_t* lb  = lB + t * 8;
  bf16_t* lb2 = lb + 2048;

  const bf16_t* raBase = lA + (wm + l15) * 32 + l4 * 8;
  const bf16_t* rbBase = lB + (wn + l15) * 32 + l4 * 8;

  for (int k0 = 0; k0 < K; k0 += 32) {
    gload_lds16(ga, la);  gload_lds16(ga2, la2);
    gload_lds16(gb, lb);  gload_lds16(gb2, lb2);
    ga += 32; ga2 += 32; gb += 32; gb2 += 32;
    __syncthreads();
    bf16x8 af[4], bq[4];
    #pragma unroll
    for (int f = 0; f < 4; ++f) {
      af[f] = *(const bf16x8*)(raBase + f * 512);
      bq[f] = *(const bf16x8*)(rbBase + f * 512);
    }
    #pragma unroll
    for (int i = 0; i < 4; ++i)
      #pragma unroll
      for (int j = 0; j < 4; ++j)
        acc[i][j] = __builtin_amdgcn_mfma_f32_16x16x32_bf16(af[i], bq[j], acc[i][j], 0, 0, 0);
    __syncthreads();
  }

  #pragma unroll
  for (int i = 0; i < 4; ++i) {
    int row = m0 + wm + i * 16 + l4 * 4;
    #pragma unroll
    for (int j = 0; j < 4; ++j) {
      int col = n0 + wn + j * 16 + l15;
      #pragma unroll
      for (int r = 0; r < 4; ++r) {
        size_t idx = (size_t)(row + r) * N + col;
        float v = acc[i][j][r];
        if (resid) v += resid[idx];
        C[idx] = v;
      }
    }
  }
}

// ---------------- prep: softplus(dt), decay, conv4+silu, dtx ----------------
__global__ __launch_bounds__(256) void prep_kernel(const float* __restrict__ zx,
                                                   const float* __restrict__ conv_w,
                                                   const float* __restrict__ conv_b,
                                                   const float* __restrict__ A_log,
                                                   float* __restrict__ decay,
                                                   float* __restrict__ dtx) {
  int idx = blockIdx.x * 256 + threadIdx.x;     // (b,t,h) linear over 4096*1024
  int h  = idx & (HEADS - 1);
  int bt = idx >> 10;
  int t  = bt & (LSEQ - 1);
  const float* row = zx + (size_t)bt * PROJ;
  float draw = row[OFF_DT + h];
  float dt = (draw > 20.f) ? draw : log1pf(expf(draw));
  float Ah = -expf(A_log[h]);
  decay[idx] = expf(dt * Ah);
  float4 w0 = *(const float4*)(conv_w + 8 * h);
  float4 w1 = *(const float4*)(conv_w + 8 * h + 4);
  float2 cb = *(const float2*)(conv_b + 2 * h);
  float acc0 = cb.x, acc1 = cb.y;
  float w0a[4] = {w0.x, w0.y, w0.z, w0.w};
  float w1a[4] = {w1.x, w1.y, w1.z, w1.w};
  #pragma unroll
  for (int k = 0; k < 4; ++k) {
    int tt = t - 3 + k;
    if (tt >= 0) {
      float2 xv = *(const float2*)(zx + (size_t)(bt - 3 + k) * PROJ + OFF_X + 2 * h);
      acc0 = fmaf(xv.x, w0a[k], acc0);
      acc1 = fmaf(xv.y, w1a[k], acc1);
    }
  }
  float xs0 = siluf(acc0), xs1 = siluf(acc1);
  *(float2*)(dtx + 2 * (size_t)idx) = make_float2(dt * xs0, dt * xs1);
}

// ---------------- selective scan v2 ----------------
// 1 head per wave (2048 waves). Block = 4 waves = 4 consecutive heads, same b.
// lane: p = lane>>5, n-range = (lane&31)*4 (float4). B/C staged in LDS per block
// (shared by the 4 heads), groups of 8 timesteps, double-buffered, counted vmcnt.
// Reduction over 32 lanes via DPP adds (result in lanes 31 / 63).
__global__ __launch_bounds__(256) void scan_kernel(const float* __restrict__ zx,
                                                   const float* __restrict__ dec,
                                                   const float* __restrict__ dtx,
                                                   float* __restrict__ y) {
  __shared__ float sbc[2][4096];   // per buf: B rows t0..t0+7 [t*128+n] then C at +2048
  int tid  = threadIdx.x;
  int wv   = tid >> 6, lane = tid & 63;
  int b    = blockIdx.x >> 8;                       // 512 blocks
  int h    = ((blockIdx.x & 255) << 2) + wv;        // head for this wave
  int p    = lane >> 5;                             // 0/1 within head
  int nl   = (lane & 31) << 2;                      // n offset (floats)
  const float* zxb = zx + (size_t)b * LSEQ * PROJ;

  float dcur[8], xcur[8], dnxt[8], xnxt[8];
  float4 hs = make_float4(0.f, 0.f, 0.f, 0.f);

  // ---- stage + regload helpers (inlined lambdas) ----
  auto STAGE = [&](int k, int tb) {
    const float* g0 = zxb + (size_t)(tb + 2 * wv + p) * PROJ;
    int ll = (lane & 31) * 4;
    gload_lds16(g0 + OFF_B + ll, &sbc[k][(2 * wv) * 128] + lane * 4);
    gload_lds16(g0 + OFF_C + ll, &sbc[k][2048 + (2 * wv) * 128] + lane * 4);
  };
  auto REGLOAD = [&](float (&dd)[8], float (&xx)[8], int tb) {
    size_t base = ((size_t)(b * LSEQ + tb)) * HEADS + h;
    #pragma unroll
    for (int q = 0; q < 8; ++q) {
      dd[q] = dec[base + (size_t)q * HEADS];
      xx[q] = dtx[2 * (base + (size_t)q * HEADS) + p];
    }
  };
  auto GROUP = [&](int k, float (&dd)[8], float (&xx)[8],
                   float (&dn)[8], float (&xn)[8], int tb) {
    int tn = tb + 8; if (tn > LSEQ - 8) tn = LSEQ - 8;
    REGLOAD(dn, xn, tn);          // 16 loads (next group's dec/dtx)
    STAGE(k ^ 1, tn);             // 2 global_load_lds (next group's B/C)
    // drain only the CURRENT buffer's stage; keep 26 newest (8 stores + 16 reg + 2 stage) in flight
    asm volatile("s_waitcnt vmcnt(26)" ::: "memory");
    __builtin_amdgcn_s_barrier();
    const float* bB = &sbc[k][0];
    const float* bC = &sbc[k][2048];
    #pragma unroll
    for (int q = 0; q < 8; ++q) {
      float4 Bv = *(const float4*)(bB + q * 128 + nl);
      float4 Cv = *(const float4*)(bC + q * 128 + nl);
      float xt = xx[q], dv = dd[q];
      hs.x = fmaf(dv, hs.x, xt * Bv.x);
      hs.y = fmaf(dv, hs.y, xt * Bv.y);
      hs.z = fmaf(dv, hs.z, xt * Bv.z);
      hs.w = fmaf(dv, hs.w, xt * Bv.w);
      float yp = hs.x * Cv.x;
      yp = fmaf(hs.y, Cv.y, yp);
      yp = fmaf(hs.z, Cv.z, yp);
      yp = fmaf(hs.w, Cv.w, yp);
      // 32-lane DPP reduce: result in lane 31 (p=0) / lane 63 (p=1)
      yp = dpp_add<0x111, 0xf>(yp);   // row_shr:1
      yp = dpp_add<0x112, 0xf>(yp);   // row_shr:2
      yp = dpp_add<0x114, 0xf>(yp);   // row_shr:4
      yp = dpp_add<0x118, 0xf>(yp);   // row_shr:8
      yp = dpp_add<0x142, 0xa>(yp);   // row_bcast:15 into odd rows
      if ((lane & 31) == 31)
        y[((size_t)(b * LSEQ + tb + q)) * D_INNER + 2 * h + p] = yp;
    }
    __builtin_amdgcn_s_barrier();
  };

  // prologue: stage group 0 (buf 0) + its dec/dtx
  STAGE(0, 0);
  REGLOAD(dcur, xcur, 0);

  for (int g = 0; g < LSEQ / 8; g += 2) {
    GROUP(0, dcur, xcur, dnxt, xnxt, g * 8);
    GROUP(1, dnxt, xnxt, dcur, xcur, (g + 1) * 8);
  }
}

// ---------------- gate: yg = y * silu(z) -> bf16 ----------------
__global__ __launch_bounds__(256) void gate_kernel(const float* __restrict__ y,
                                                   const float* __restrict__ zx,
                                                   bf16_t* __restrict__ yg) {
  int tid = blockIdx.x * 256 + threadIdx.x;
  int row = tid >> 9;
  int c0  = (tid & 511) * 4;
  float4 yv = *(const float4*)(y  + (size_t)row * D_INNER + c0);
  float4 zv = *(const float4*)(zx + (size_t)row * PROJ + OFF_Z + c0);
  bf16x4v o;
  o[0] = (bf16_t)(yv.x * siluf(zv.x));
  o[1] = (bf16_t)(yv.y * siluf(zv.y));
  o[2] = (bf16_t)(yv.z * siluf(zv.z));
  o[3] = (bf16_t)(yv.w * siluf(zv.w));
  *(bf16x4v*)(yg + (size_t)row * D_INNER + c0) = o;
}

// ---------------- launch ----------------
extern "C" void kernel_launch(void* const* d_in, const int* in_sizes, int n_in,
                              void* d_out, int out_size, void* d_ws, size_t ws_size,
                              hipStream_t stream) {
  const float* u      = (const float*)d_in[0];
  const float* W_in   = (const float*)d_in[1];
  const float* conv_w = (const float*)d_in[2];
  const float* conv_b = (const float*)d_in[3];
  const float* W_out  = (const float*)d_in[4];
  const float* ln_g   = (const float*)d_in[5];
  const float* ln_b   = (const float*)d_in[6];
  const float* A_log  = (const float*)d_in[7];
  float* out = (float*)d_out;

  char* ws = (char*)d_ws;
  bf16_t* W_inT  = (bf16_t*)ws;  ws += (size_t)PROJ * D_MODEL * 2;
  bf16_t* W_outT = (bf16_t*)ws;  ws += (size_t)D_MODEL * D_INNER * 2;
  bf16_t* xn     = (bf16_t*)ws;  ws += (size_t)NROW * D_MODEL * 2;
  float*  zx     = (float*)ws;   ws += (size_t)NROW * PROJ * 4;
  float*  dec    = (float*)ws;   ws += (size_t)NROW * HEADS * 4;
  float*  dtx    = (float*)ws;   ws += (size_t)NROW * D_INNER * 4;
  float*  yy     = (float*)ws;   ws += (size_t)NROW * D_INNER * 4;
  bf16_t* yg     = (bf16_t*)ws;  ws += (size_t)NROW * D_INNER * 2;

  dim3 tb(32, 8);
  transpose_kernel<<<dim3(PROJ / 32, D_MODEL / 32), tb, 0, stream>>>(W_in, W_inT, D_MODEL, PROJ);
  transpose_kernel<<<dim3(D_MODEL / 32, D_INNER / 32), tb, 0, stream>>>(W_out, W_outT, D_INNER, D_MODEL);
  ln_kernel<<<NROW, 256, 0, stream>>>(u, ln_g, ln_b, xn);
  gemm_bt<<<(NROW / 128) * (PROJ / 128), 256, 0, stream>>>(xn, W_inT, zx, NROW, PROJ, D_MODEL, nullptr);
  prep_kernel<<<NROW * HEADS / 256, 256, 0, stream>>>(zx, conv_w, conv_b, A_log, dec, dtx);
  scan_kernel<<<512, 256, 0, stream>>>(zx, dec, dtx, yy);
  gate_kernel<<<NROW * D_INNER / 4 / 256, 256, 0, stream>>>(yy, zx, yg);
  gemm_bt<<<(NROW / 128) * (D_MODEL / 128), 256, 0, stream>>>(yg, W_outT, out, NROW, D_MODEL, D_INNER, u);
}

// Round 4
// 468.393 us; speedup vs baseline: 2.2293x; 1.4173x over previous
//
#include <hip/hip_runtime.h>
#include <hip/hip_bf16.h>
#include <stdint.h>

// ---------------- types ----------------
typedef __bf16 bf16_t;
typedef bf16_t bf16x8 __attribute__((ext_vector_type(8)));
typedef bf16_t bf16x4 __attribute__((ext_vector_type(4)));
typedef bf16_t bf16x2 __attribute__((ext_vector_type(2)));
typedef float  f32x4  __attribute__((ext_vector_type(4)));

#define D_MODEL 1024
#define D_STATE 128
#define D_INNER 2048
#define HEADS   1024
#define PROJ    5376
#define LSEQ    2048
#define BATCH   2
#define NROW    (BATCH*LSEQ)   // 4096
#define QCH     64             // chunk length
#define NC      (LSEQ/QCH)     // 32 chunks per sequence

// offsets within a zxbcdt row
#define OFF_X   0
#define OFF_Z   2048
#define OFF_B   4096
#define OFF_C   4224
#define OFF_DT  4352

typedef __attribute__((address_space(1))) void void_as1;
typedef __attribute__((address_space(3))) void void_as3;

__device__ __forceinline__ void gload_lds16(const void* g, void* l) {
  __builtin_amdgcn_global_load_lds((void_as1*)(uintptr_t)g,
                                   (void_as3*)(uint32_t)(uintptr_t)l,
                                   16, 0, 0);
}

__device__ __forceinline__ float siluf(float v) { return v / (1.f + expf(-v)); }

template<int CTRL, int RM>
__device__ __forceinline__ float dpp_add(float x) {
  int s = __builtin_amdgcn_update_dpp(0, __float_as_int(x), CTRL, RM, 0xf, true);
  return x + __int_as_float(s);
}

// ---------------- transpose fp32 (R x C) -> bf16 (C x R) ----------------
__global__ __launch_bounds__(256) void transpose_kernel(const float* __restrict__ src,
                                                        bf16_t* __restrict__ dst,
                                                        int R, int C) {
  __shared__ float tile[32][33];
  int c0 = blockIdx.x * 32, r0 = blockIdx.y * 32;
  int tx = threadIdx.x, ty = threadIdx.y;
  #pragma unroll
  for (int i = ty; i < 32; i += 8)
    tile[i][tx] = src[(size_t)(r0 + i) * C + c0 + tx];
  __syncthreads();
  #pragma unroll
  for (int i = ty; i < 32; i += 8)
    dst[(size_t)(c0 + i) * R + r0 + tx] = (bf16_t)tile[tx][i];
}

// ---------------- layernorm -> bf16 ----------------
__global__ __launch_bounds__(256) void ln_kernel(const float* __restrict__ u,
                                                 const float* __restrict__ g,
                                                 const float* __restrict__ bb,
                                                 bf16_t* __restrict__ xn) {
  int row = blockIdx.x;
  int t = threadIdx.x;
  float4 v = ((const float4*)(u + (size_t)row * D_MODEL))[t];
  float s  = v.x + v.y + v.z + v.w;
  float s2 = v.x*v.x + v.y*v.y + v.z*v.z + v.w*v.w;
  #pragma unroll
  for (int m = 1; m < 64; m <<= 1) { s += __shfl_xor(s, m, 64); s2 += __shfl_xor(s2, m, 64); }
  __shared__ float ws[8];
  int wv = t >> 6, lane = t & 63;
  if (lane == 0) { ws[wv] = s; ws[4 + wv] = s2; }
  __syncthreads();
  s  = ws[0] + ws[1] + ws[2] + ws[3];
  s2 = ws[4] + ws[5] + ws[6] + ws[7];
  float mean = s * (1.f / D_MODEL);
  float var  = s2 * (1.f / D_MODEL) - mean * mean;
  float rstd = rsqrtf(var + 1e-5f);
  float4 gv = ((const float4*)g)[t];
  float4 bv = ((const float4*)bb)[t];
  bf16x4 o;
  o[0] = (bf16_t)((v.x - mean) * rstd * gv.x + bv.x);
  o[1] = (bf16_t)((v.y - mean) * rstd * gv.y + bv.y);
  o[2] = (bf16_t)((v.z - mean) * rstd * gv.z + bv.z);
  o[3] = (bf16_t)((v.w - mean) * rstd * gv.w + bv.w);
  *(bf16x4*)(xn + (size_t)row * D_MODEL + t * 4) = o;
}

// ---------------- GEMM  C[M,N] = A[M,K] * BT[N,K]^T  (+optional fp32 resid) ----
// 128x128 tile, 4 waves, mfma 16x16x32 bf16, BK=32. Batched via tilesPerBatch.
template<typename CT>
__global__ __launch_bounds__(256) void gemm_bt(const bf16_t* __restrict__ A,
                                               const bf16_t* __restrict__ BT,
                                               CT* __restrict__ C,
                                               int M, int N, int K,
                                               const float* __restrict__ resid,
                                               int tilesPerBatch,
                                               long long sA, long long sB, long long sC) {
  __shared__ bf16_t lA[128 * 32];
  __shared__ bf16_t lB[128 * 32];
  int bat = blockIdx.x / tilesPerBatch;
  int tl  = blockIdx.x % tilesPerBatch;
  A += (size_t)bat * sA; BT += (size_t)bat * sB; C += (size_t)bat * sC;
  int ntile = N >> 7;
  int tm = tl / ntile, tn = tl % ntile;
  int m0 = tm << 7, n0 = tn << 7;
  int t = threadIdx.x;
  int wv = t >> 6, lane = t & 63;
  int wm = (wv >> 1) << 6, wn = (wv & 1) << 6;
  int l15 = lane & 15, l4 = lane >> 4;

  f32x4 acc[4][4];
  #pragma unroll
  for (int i = 0; i < 4; ++i)
    #pragma unroll
    for (int j = 0; j < 4; ++j) acc[i][j] = (f32x4){0.f, 0.f, 0.f, 0.f};

  int sr = t >> 2;
  int sk = (t & 3) * 8;
  const bf16_t* ga  = A  + (size_t)(m0 + sr) * K + sk;
  const bf16_t* ga2 = ga + (size_t)64 * K;
  const bf16_t* gb  = BT + (size_t)(n0 + sr) * K + sk;
  const bf16_t* gb2 = gb + (size_t)64 * K;
  bf16_t* la  = lA + t * 8;
  bf16_t* la2 = la + 2048;
  bf16_t* lb  = lB + t * 8;
  bf16_t* lb2 = lb + 2048;

  const bf16_t* raBase = lA + (wm + l15) * 32 + l4 * 8;
  const bf16_t* rbBase = lB + (wn + l15) * 32 + l4 * 8;

  for (int k0 = 0; k0 < K; k0 += 32) {
    gload_lds16(ga, la);  gload_lds16(ga2, la2);
    gload_lds16(gb, lb);  gload_lds16(gb2, lb2);
    ga += 32; ga2 += 32; gb += 32; gb2 += 32;
    __syncthreads();
    bf16x8 af[4], bq[4];
    #pragma unroll
    for (int f = 0; f < 4; ++f) {
      af[f] = *(const bf16x8*)(raBase + f * 512);
      bq[f] = *(const bf16x8*)(rbBase + f * 512);
    }
    #pragma unroll
    for (int i = 0; i < 4; ++i)
      #pragma unroll
      for (int j = 0; j < 4; ++j)
        acc[i][j] = __builtin_amdgcn_mfma_f32_16x16x32_bf16(af[i], bq[j], acc[i][j], 0, 0, 0);
    __syncthreads();
  }

  #pragma unroll
  for (int i = 0; i < 4; ++i) {
    int row = m0 + wm + i * 16 + l4 * 4;
    #pragma unroll
    for (int j = 0; j < 4; ++j) {
      int col = n0 + wn + j * 16 + l15;
      #pragma unroll
      for (int r = 0; r < 4; ++r) {
        size_t idx = (size_t)(row + r) * N + col;
        float v = acc[i][j][r];
        if (resid) v += resid[idx];
        C[idx] = (CT)v;
      }
    }
  }
}

// ---------------- prep: softplus(dt) -> dta, conv4+silu -> dtx (bf16) --------
__global__ __launch_bounds__(256) void prep_kernel(const bf16_t* __restrict__ zxb,
                                                   const float* __restrict__ conv_w,
                                                   const float* __restrict__ conv_b,
                                                   const float* __restrict__ A_log,
                                                   float* __restrict__ dta,
                                                   bf16_t* __restrict__ dtx) {
  int idx = blockIdx.x * 256 + threadIdx.x;     // (bt,h) over 4096*1024
  int h  = idx & (HEADS - 1);
  int bt = idx >> 10;
  int t  = bt & (LSEQ - 1);
  float draw = (float)zxb[(size_t)bt * PROJ + OFF_DT + h];
  float dt = (draw > 20.f) ? draw : log1pf(expf(draw));
  float Ah = -expf(A_log[h]);
  dta[idx] = dt * Ah;
  float4 w0 = *(const float4*)(conv_w + 8 * h);
  float4 w1 = *(const float4*)(conv_w + 8 * h + 4);
  float2 cb = *(const float2*)(conv_b + 2 * h);
  float acc0 = cb.x, acc1 = cb.y;
  float w0a[4] = {w0.x, w0.y, w0.z, w0.w};
  float w1a[4] = {w1.x, w1.y, w1.z, w1.w};
  #pragma unroll
  for (int k = 0; k < 4; ++k) {
    int tt = t - 3 + k;
    if (tt >= 0) {
      bf16x2 xv = *(const bf16x2*)(zxb + (size_t)(bt - 3 + k) * PROJ + OFF_X + 2 * h);
      acc0 = fmaf((float)xv[0], w0a[k], acc0);
      acc1 = fmaf((float)xv[1], w1a[k], acc1);
    }
  }
  float xs0 = siluf(acc0), xs1 = siluf(acc1);
  bf16x2 o; o[0] = (bf16_t)(dt * xs0); o[1] = (bf16_t)(dt * xs1);
  *(bf16x2*)(dtx + 2 * (size_t)idx) = o;
}

// ---------------- kg: per (b,c)  GT[j][i] = B_j . C_i  (fp32) + BTc[n][j] ----
__global__ __launch_bounds__(256) void kg_kernel(const bf16_t* __restrict__ zxb,
                                                 float* __restrict__ GT,
                                                 bf16_t* __restrict__ BTc) {
  __shared__ bf16_t lB[QCH * 128];
  __shared__ bf16_t lC[QCH * 128];
  int bc = blockIdx.x;              // b*NC + c
  int b = bc / NC, c = bc % NC;
  int t = threadIdx.x;
  size_t rowbase = ((size_t)b * LSEQ + c * QCH);
  // stage B,C chunks (64 rows x 128 bf16 each)
  #pragma unroll
  for (int p = 0; p < 4; ++p) {
    int row = p * 16 + (t >> 4);
    int eo  = (t & 15) * 8;
    gload_lds16(zxb + (rowbase + row) * PROJ + OFF_B + eo, lB + p * 2048 + t * 8);
    gload_lds16(zxb + (rowbase + row) * PROJ + OFF_C + eo, lC + p * 2048 + t * 8);
  }
  __syncthreads();
  int wv = t >> 6, lane = t & 63;
  int l15 = lane & 15, l4 = lane >> 4;
  f32x4 acc[4];
  #pragma unroll
  for (int i = 0; i < 4; ++i) acc[i] = (f32x4){0.f, 0.f, 0.f, 0.f};
  #pragma unroll
  for (int ks = 0; ks < 4; ++ks) {
    bf16x8 af = *(const bf16x8*)(lB + (16 * wv + l15) * 128 + ks * 32 + l4 * 8);
    #pragma unroll
    for (int it = 0; it < 4; ++it) {
      bf16x8 bq = *(const bf16x8*)(lC + (16 * it + l15) * 128 + ks * 32 + l4 * 8);
      acc[it] = __builtin_amdgcn_mfma_f32_16x16x32_bf16(af, bq, acc[it], 0, 0, 0);
    }
  }
  float* gout = GT + (size_t)bc * 4096;
  #pragma unroll
  for (int it = 0; it < 4; ++it) {
    int col = it * 16 + l15;
    #pragma unroll
    for (int r = 0; r < 4; ++r) {
      int j = 16 * wv + l4 * 4 + r;
      gout[j * 64 + col] = acc[it][r];
    }
  }
  // write BTc[n][j] = B[j][n] transposed, bf16
  bf16_t* bto = BTc + (size_t)bc * (128 * QCH);
  int n = t >> 1, j0 = (t & 1) * 32;
  #pragma unroll
  for (int jj = 0; jj < 32; ++jj)
    bto[n * QCH + j0 + jj] = lB[(j0 + jj) * 128 + n];
}

// ---------------- local: per (b,c,head) intra-chunk y + S,cd,D -------------
// block = 8 waves = 8 heads; lane = timestep i within chunk.
__global__ __launch_bounds__(512) void local_kernel(const float* __restrict__ GT,
                                                    const float* __restrict__ dta,
                                                    const bf16_t* __restrict__ dtx,
                                                    float* __restrict__ y,
                                                    bf16_t* __restrict__ S,
                                                    bf16_t* __restrict__ cdb,
                                                    float* __restrict__ Dch) {
  __shared__ float sGT[4096];      // GT[j][i]
  __shared__ float4 cav[8][QCH];   // per head: (ca_j, v0_j, v1_j, -)
  __shared__ float sy[QCH * 16];   // 64 t x 16 hp transpose buffer
  int t = threadIdx.x;
  int wv = t >> 6, l = t & 63;
  int hg = blockIdx.x & 127;
  int c  = (blockIdx.x >> 7) & (NC - 1);
  int b  = blockIdx.x >> 12;
  int bc = b * NC + c;
  int h  = hg * 8 + wv;

  // stage GT (16 KB) : 512 lanes x 16B x 2
  gload_lds16(GT + (size_t)bc * 4096 + t * 4, sGT + t * 4);
  gload_lds16(GT + (size_t)bc * 4096 + 2048 + t * 4, sGT + 2048 + t * 4);

  int tIdx = c * QCH + l;
  size_t bt = (size_t)b * LSEQ + tIdx;
  float dtal = dta[bt * HEADS + h];
  bf16x2 vv = *(const bf16x2*)(dtx + bt * D_INNER + 2 * h);
  float v0 = (float)vv[0], v1 = (float)vv[1];

  // inclusive prefix sum of dta over 64 lanes -> ca
  float ca = dtal;
  ca = dpp_add<0x111, 0xf>(ca);   // row_shr:1
  ca = dpp_add<0x112, 0xf>(ca);   // row_shr:2
  ca = dpp_add<0x114, 0xf>(ca);   // row_shr:4
  ca = dpp_add<0x118, 0xf>(ca);   // row_shr:8
  ca = dpp_add<0x142, 0xa>(ca);   // row_bcast:15 -> rows 1,3
  ca = dpp_add<0x143, 0xc>(ca);   // row_bcast:31 -> rows 2,3

  float cdl = expf(ca);
  cdb[((size_t)b * HEADS + h) * LSEQ + tIdx] = (bf16_t)cdl;
  float calast = __shfl(ca, 63);
  float sc = expf(calast - ca);
  bf16_t* srow = S + ((size_t)bc * D_INNER + 2 * h) * QCH + l;
  srow[0]   = (bf16_t)(sc * v0);
  srow[QCH] = (bf16_t)(sc * v1);
  if (l == 63) Dch[((size_t)b * HEADS + h) * NC + c] = cdl;
  cav[wv][l] = make_float4(ca, v0, v1, 0.f);
  __syncthreads();   // GT staged (drains vmcnt) + cav visible

  float y0 = 0.f, y1 = 0.f;
  #pragma unroll 4
  for (int j = 0; j < QCH; ++j) {
    float4 cj = cav[wv][j];
    float arg = (j <= l) ? (ca - cj.x) : -1e30f;
    float e = expf(arg);
    float g = e * sGT[j * 64 + l];
    y0 = fmaf(g, cj.y, y0);
    y1 = fmaf(g, cj.z, y1);
  }
  sy[l * 16 + wv * 2]     = y0;
  sy[l * 16 + wv * 2 + 1] = y1;
  __syncthreads();
  // write y tile: 64 t rows x 16 hp cols
  int rowt = t >> 3, cc = (t & 7) * 2;
  float2 o = make_float2(sy[rowt * 16 + cc], sy[rowt * 16 + cc + 1]);
  *(float2*)(y + ((size_t)b * LSEQ + c * QCH + rowt) * D_INNER + hg * 16 + cc) = o;
}

// ---------------- state scan over chunks (in-place Hloc -> Hin, bf16) -------
__global__ __launch_bounds__(256) void state_kernel(bf16_t* __restrict__ Hst,
                                                    const float* __restrict__ Dch) {
  int g = blockIdx.x * 256 + threadIdx.x;   // (b, hp, nq) : 2*2048*32
  int nq = g & 31;
  int hp = (g >> 5) & (D_INNER - 1);
  int b  = g >> 16;
  int h  = hp >> 1;
  const float* Dp = Dch + ((size_t)b * HEADS + h) * NC;
  float4 cur = make_float4(0.f, 0.f, 0.f, 0.f);
  for (int c = 0; c < NC; ++c) {
    size_t idx = (((size_t)(b * NC + c) * D_INNER) + hp) * D_STATE + nq * 4;
    bf16x4 old = *(bf16x4*)(Hst + idx);
    bf16x4 w;
    w[0] = (bf16_t)cur.x; w[1] = (bf16_t)cur.y; w[2] = (bf16_t)cur.z; w[3] = (bf16_t)cur.w;
    *(bf16x4*)(Hst + idx) = w;
    float d = Dp[c];
    cur.x = fmaf(d, cur.x, (float)old[0]);
    cur.y = fmaf(d, cur.y, (float)old[1]);
    cur.z = fmaf(d, cur.z, (float)old[2]);
    cur.w = fmaf(d, cur.w, (float)old[3]);
  }
}

// ---------------- ycross: y += cd_i * (C_i . Hin[hp])  per (b,c) ------------
// tile 64(M=i) x 256(N=hp), 4 waves each 64x64, K=128
__global__ __launch_bounds__(256) void ycross_kernel(const bf16_t* __restrict__ zxb,
                                                     const bf16_t* __restrict__ Hst,
                                                     const bf16_t* __restrict__ cdb,
                                                     float* __restrict__ y) {
  __shared__ bf16_t lA[QCH * 32];
  __shared__ bf16_t lB[256 * 32];
  int nt = blockIdx.x & 7;
  int c  = (blockIdx.x >> 3) & (NC - 1);
  int b  = blockIdx.x >> 8;
  int bc = b * NC + c;
  int n0 = nt * 256;
  int t = threadIdx.x;
  int wv = t >> 6, lane = t & 63;
  int l15 = lane & 15, l4 = lane >> 4;
  size_t rowbase = (size_t)b * LSEQ + c * QCH;

  f32x4 acc[4][4];
  #pragma unroll
  for (int i = 0; i < 4; ++i)
    #pragma unroll
    for (int j = 0; j < 4; ++j) acc[i][j] = (f32x4){0.f, 0.f, 0.f, 0.f};

  int sr = t >> 2, sk = (t & 3) * 8;
  for (int ks = 0; ks < 4; ++ks) {
    int k0 = ks * 32;
    gload_lds16(zxb + (rowbase + sr) * PROJ + OFF_C + k0 + sk, lA + t * 8);
    #pragma unroll
    for (int p = 0; p < 4; ++p)
      gload_lds16(Hst + ((size_t)bc * D_INNER + n0 + p * 64 + sr) * D_STATE + k0 + sk,
                  lB + p * 2048 + t * 8);
    __syncthreads();
    #pragma unroll
    for (int i = 0; i < 4; ++i) {
      bf16x8 af = *(const bf16x8*)(lA + (i * 16 + l15) * 32 + l4 * 8);
      #pragma unroll
      for (int j = 0; j < 4; ++j) {
        bf16x8 bq = *(const bf16x8*)(lB + (wv * 64 + j * 16 + l15) * 32 + l4 * 8);
        acc[i][j] = __builtin_amdgcn_mfma_f32_16x16x32_bf16(af, bq, acc[i][j], 0, 0, 0);
      }
    }
    __syncthreads();
  }

  #pragma unroll
  for (int i = 0; i < 4; ++i) {
    int row = i * 16 + l4 * 4;
    #pragma unroll
    for (int j = 0; j < 4; ++j) {
      int col = n0 + wv * 64 + j * 16 + l15;   // hp
      int h = col >> 1;
      bf16x4 cd4 = *(const bf16x4*)(cdb + ((size_t)b * HEADS + h) * LSEQ + c * QCH + row);
      #pragma unroll
      for (int r = 0; r < 4; ++r) {
        size_t idx = (rowbase + row + r) * D_INNER + col;
        y[idx] += (float)cd4[r] * acc[i][j][r];
      }
    }
  }
}

// ---------------- gate: yg = y * silu(z) -> bf16 ----------------
__global__ __launch_bounds__(256) void gate_kernel(const float* __restrict__ y,
                                                   const bf16_t* __restrict__ zxb,
                                                   bf16_t* __restrict__ yg) {
  int tid = blockIdx.x * 256 + threadIdx.x;
  int row = tid >> 9;
  int c0  = (tid & 511) * 4;
  float4 yv = *(const float4*)(y + (size_t)row * D_INNER + c0);
  bf16x4 zv = *(const bf16x4*)(zxb + (size_t)row * PROJ + OFF_Z + c0);
  bf16x4 o;
  o[0] = (bf16_t)(yv.x * siluf((float)zv[0]));
  o[1] = (bf16_t)(yv.y * siluf((float)zv[1]));
  o[2] = (bf16_t)(yv.z * siluf((float)zv[2]));
  o[3] = (bf16_t)(yv.w * siluf((float)zv[3]));
  *(bf16x4*)(yg + (size_t)row * D_INNER + c0) = o;
}

// ---------------- launch ----------------
extern "C" void kernel_launch(void* const* d_in, const int* in_sizes, int n_in,
                              void* d_out, int out_size, void* d_ws, size_t ws_size,
                              hipStream_t stream) {
  const float* u      = (const float*)d_in[0];
  const float* W_in   = (const float*)d_in[1];
  const float* conv_w = (const float*)d_in[2];
  const float* conv_b = (const float*)d_in[3];
  const float* W_out  = (const float*)d_in[4];
  const float* ln_g   = (const float*)d_in[5];
  const float* ln_b   = (const float*)d_in[6];
  const float* A_log  = (const float*)d_in[7];
  float* out = (float*)d_out;

  char* ws = (char*)d_ws;
  bf16_t* W_inT  = (bf16_t*)ws;  ws += (size_t)PROJ * D_MODEL * 2;        // 11.0 MB
  bf16_t* W_outT = (bf16_t*)ws;  ws += (size_t)D_MODEL * D_INNER * 2;     //  4.2 MB
  bf16_t* xn     = (bf16_t*)ws;  ws += (size_t)NROW * D_MODEL * 2;        //  8.4 MB
  bf16_t* zxb    = (bf16_t*)ws;  ws += (size_t)NROW * PROJ * 2;           // 44.0 MB
  float*  dta    = (float*)ws;   ws += (size_t)NROW * HEADS * 4;          // 16.8 MB
  bf16_t* dtx    = (bf16_t*)ws;  ws += (size_t)NROW * D_INNER * 2;        // 16.8 MB
  float*  yy     = (float*)ws;   ws += (size_t)NROW * D_INNER * 4;        // 33.6 MB
  bf16_t* yg     = (bf16_t*)ws;  ws += (size_t)NROW * D_INNER * 2;        // 16.8 MB
  float*  GT     = (float*)ws;   ws += (size_t)BATCH * NC * 4096 * 4;     //  1.0 MB
  bf16_t* BTc    = (bf16_t*)ws;  ws += (size_t)BATCH * NC * 128 * QCH * 2;//  1.0 MB
  bf16_t* S      = (bf16_t*)ws;  ws += (size_t)BATCH * NC * D_INNER * QCH * 2; // 16.8 MB
  bf16_t* cdb    = (bf16_t*)ws;  ws += (size_t)BATCH * HEADS * LSEQ * 2;  //  8.4 MB
  float*  Dch    = (float*)ws;   ws += (size_t)BATCH * HEADS * NC * 4;    //  0.3 MB
  bf16_t* Hst    = (bf16_t*)ws;  ws += (size_t)BATCH * NC * D_INNER * D_STATE * 2; // 33.6 MB

  dim3 tb(32, 8);
  transpose_kernel<<<dim3(PROJ / 32, D_MODEL / 32), tb, 0, stream>>>(W_in, W_inT, D_MODEL, PROJ);
  transpose_kernel<<<dim3(D_MODEL / 32, D_INNER / 32), tb, 0, stream>>>(W_out, W_outT, D_INNER, D_MODEL);
  ln_kernel<<<NROW, 256, 0, stream>>>(u, ln_g, ln_b, xn);
  gemm_bt<bf16_t><<<(NROW / 128) * (PROJ / 128), 256, 0, stream>>>(
      xn, W_inT, zxb, NROW, PROJ, D_MODEL, nullptr, (NROW / 128) * (PROJ / 128), 0, 0, 0);
  prep_kernel<<<NROW * HEADS / 256, 256, 0, stream>>>(zxb, conv_w, conv_b, A_log, dta, dtx);
  kg_kernel<<<BATCH * NC, 256, 0, stream>>>(zxb, GT, BTc);
  local_kernel<<<BATCH * NC * 128, 512, 0, stream>>>(GT, dta, dtx, yy, S, cdb, Dch);
  gemm_bt<bf16_t><<<BATCH * NC * 16, 256, 0, stream>>>(
      S, BTc, Hst, D_INNER, D_STATE, QCH, nullptr, 16,
      (long long)D_INNER * QCH, (long long)128 * QCH, (long long)D_INNER * D_STATE);
  state_kernel<<<BATCH * D_INNER * 32 / 256, 256, 0, stream>>>(Hst, Dch);
  ycross_kernel<<<BATCH * NC * 8, 256, 0, stream>>>(zxb, Hst, cdb, yy);
  gate_kernel<<<NROW * D_INNER / 4 / 256, 256, 0, stream>>>(yy, zxb, yg);
  gemm_bt<float><<<(NROW / 128) * (D_MODEL / 128), 256, 0, stream>>>(
      yg, W_outT, out, NROW, D_MODEL, D_INNER, u, (NROW / 128) * (D_MODEL / 128), 0, 0, 0);
}

// Round 5
// 412.171 us; speedup vs baseline: 2.5334x; 1.1364x over previous
//
#include <hip/hip_runtime.h>
#include <hip/hip_bf16.h>
#include <stdint.h>

// ---------------- types ----------------
typedef __bf16 bf16_t;
typedef bf16_t bf16x8 __attribute__((ext_vector_type(8)));
typedef bf16_t bf16x4 __attribute__((ext_vector_type(4)));
typedef bf16_t bf16x2 __attribute__((ext_vector_type(2)));
typedef float  f32x4  __attribute__((ext_vector_type(4)));

#define D_MODEL 1024
#define D_STATE 128
#define D_INNER 2048
#define HEADS   1024
#define PROJ    5376
#define LSEQ    2048
#define BATCH   2
#define NROW    (BATCH*LSEQ)   // 4096
#define QCH     64             // chunk length
#define NC      (LSEQ/QCH)     // 32 chunks per sequence

// offsets within a zxbcdt row
#define OFF_X   0
#define OFF_Z   2048
#define OFF_B   4096
#define OFF_C   4224
#define OFF_DT  4352

#define LOG2E 1.44269504088896340736f

typedef __attribute__((address_space(1))) void void_as1;
typedef __attribute__((address_space(3))) void void_as3;

__device__ __forceinline__ void gload_lds16(const void* g, void* l) {
  __builtin_amdgcn_global_load_lds((void_as1*)(uintptr_t)g,
                                   (void_as3*)(uint32_t)(uintptr_t)l,
                                   16, 0, 0);
}

__device__ __forceinline__ float siluf(float v) { return v / (1.f + expf(-v)); }

// raw hardware 2^x
__device__ __forceinline__ float exp2_fast(float x) {
  float r;
  asm("v_exp_f32 %0, %1" : "=v"(r) : "v"(x));
  return r;
}

__device__ __forceinline__ float rdlane(float v, int l) {
  return __int_as_float(__builtin_amdgcn_readlane(__float_as_int(v), l));
}

template<int CTRL, int RM>
__device__ __forceinline__ float dpp_add(float x) {
  int s = __builtin_amdgcn_update_dpp(0, __float_as_int(x), CTRL, RM, 0xf, true);
  return x + __int_as_float(s);
}

// ---------------- transpose fp32 (R x C) -> bf16 (C x R) ----------------
__global__ __launch_bounds__(256) void transpose_kernel(const float* __restrict__ src,
                                                        bf16_t* __restrict__ dst,
                                                        int R, int C) {
  __shared__ float tile[32][33];
  int c0 = blockIdx.x * 32, r0 = blockIdx.y * 32;
  int tx = threadIdx.x, ty = threadIdx.y;
  #pragma unroll
  for (int i = ty; i < 32; i += 8)
    tile[i][tx] = src[(size_t)(r0 + i) * C + c0 + tx];
  __syncthreads();
  #pragma unroll
  for (int i = ty; i < 32; i += 8)
    dst[(size_t)(c0 + i) * R + r0 + tx] = (bf16_t)tile[tx][i];
}

// ---------------- layernorm -> bf16 ----------------
__global__ __launch_bounds__(256) void ln_kernel(const float* __restrict__ u,
                                                 const float* __restrict__ g,
                                                 const float* __restrict__ bb,
                                                 bf16_t* __restrict__ xn) {
  int row = blockIdx.x;
  int t = threadIdx.x;
  float4 v = ((const float4*)(u + (size_t)row * D_MODEL))[t];
  float s  = v.x + v.y + v.z + v.w;
  float s2 = v.x*v.x + v.y*v.y + v.z*v.z + v.w*v.w;
  #pragma unroll
  for (int m = 1; m < 64; m <<= 1) { s += __shfl_xor(s, m, 64); s2 += __shfl_xor(s2, m, 64); }
  __shared__ float ws[8];
  int wv = t >> 6, lane = t & 63;
  if (lane == 0) { ws[wv] = s; ws[4 + wv] = s2; }
  __syncthreads();
  s  = ws[0] + ws[1] + ws[2] + ws[3];
  s2 = ws[4] + ws[5] + ws[6] + ws[7];
  float mean = s * (1.f / D_MODEL);
  float var  = s2 * (1.f / D_MODEL) - mean * mean;
  float rstd = rsqrtf(var + 1e-5f);
  float4 gv = ((const float4*)g)[t];
  float4 bv = ((const float4*)bb)[t];
  bf16x4 o;
  o[0] = (bf16_t)((v.x - mean) * rstd * gv.x + bv.x);
  o[1] = (bf16_t)((v.y - mean) * rstd * gv.y + bv.y);
  o[2] = (bf16_t)((v.z - mean) * rstd * gv.z + bv.z);
  o[3] = (bf16_t)((v.w - mean) * rstd * gv.w + bv.w);
  *(bf16x4*)(xn + (size_t)row * D_MODEL + t * 4) = o;
}

// ---------------- GEMM  C[M,N] = A[M,K] * BT[N,K]^T  (+optional fp32 resid) ----
template<typename CT>
__global__ __launch_bounds__(256) void gemm_bt(const bf16_t* __restrict__ A,
                                               const bf16_t* __restrict__ BT,
                                               CT* __restrict__ C,
                                               int M, int N, int K,
                                               const float* __restrict__ resid,
                                               int tilesPerBatch,
                                               long long sA, long long sB, long long sC) {
  __shared__ bf16_t lA[128 * 32];
  __shared__ bf16_t lB[128 * 32];
  int bat = blockIdx.x / tilesPerBatch;
  int tl  = blockIdx.x % tilesPerBatch;
  A += (size_t)bat * sA; BT += (size_t)bat * sB; C += (size_t)bat * sC;
  int ntile = N >> 7;
  int tm = tl / ntile, tn = tl % ntile;
  int m0 = tm << 7, n0 = tn << 7;
  int t = threadIdx.x;
  int wv = t >> 6, lane = t & 63;
  int wm = (wv >> 1) << 6, wn = (wv & 1) << 6;
  int l15 = lane & 15, l4 = lane >> 4;

  f32x4 acc[4][4];
  #pragma unroll
  for (int i = 0; i < 4; ++i)
    #pragma unroll
    for (int j = 0; j < 4; ++j) acc[i][j] = (f32x4){0.f, 0.f, 0.f, 0.f};

  int sr = t >> 2;
  int sk = (t & 3) * 8;
  const bf16_t* ga  = A  + (size_t)(m0 + sr) * K + sk;
  const bf16_t* ga2 = ga + (size_t)64 * K;
  const bf16_t* gb  = BT + (size_t)(n0 + sr) * K + sk;
  const bf16_t* gb2 = gb + (size_t)64 * K;
  bf16_t* la  = lA + t * 8;
  bf16_t* la2 = la + 2048;
  bf16_t* lb  = lB + t * 8;
  bf16_t* lb2 = lb + 2048;

  const bf16_t* raBase = lA + (wm + l15) * 32 + l4 * 8;
  const bf16_t* rbBase = lB + (wn + l15) * 32 + l4 * 8;

  for (int k0 = 0; k0 < K; k0 += 32) {
    gload_lds16(ga, la);  gload_lds16(ga2, la2);
    gload_lds16(gb, lb);  gload_lds16(gb2, lb2);
    ga += 32; ga2 += 32; gb += 32; gb2 += 32;
    __syncthreads();
    bf16x8 af[4], bq[4];
    #pragma unroll
    for (int f = 0; f < 4; ++f) {
      af[f] = *(const bf16x8*)(raBase + f * 512);
      bq[f] = *(const bf16x8*)(rbBase + f * 512);
    }
    #pragma unroll
    for (int i = 0; i < 4; ++i)
      #pragma unroll
      for (int j = 0; j < 4; ++j)
        acc[i][j] = __builtin_amdgcn_mfma_f32_16x16x32_bf16(af[i], bq[j], acc[i][j], 0, 0, 0);
    __syncthreads();
  }

  #pragma unroll
  for (int i = 0; i < 4; ++i) {
    int row = m0 + wm + i * 16 + l4 * 4;
    #pragma unroll
    for (int j = 0; j < 4; ++j) {
      int col = n0 + wn + j * 16 + l15;
      #pragma unroll
      for (int r = 0; r < 4; ++r) {
        size_t idx = (size_t)(row + r) * N + col;
        float v = acc[i][j][r];
        if (resid) v += resid[idx];
        C[idx] = (CT)v;
      }
    }
  }
}

// ---------------- prep: softplus(dt) -> dta, conv4+silu -> dtx (bf16) --------
__global__ __launch_bounds__(256) void prep_kernel(const bf16_t* __restrict__ zxb,
                                                   const float* __restrict__ conv_w,
                                                   const float* __restrict__ conv_b,
                                                   const float* __restrict__ A_log,
                                                   float* __restrict__ dta,
                                                   bf16_t* __restrict__ dtx) {
  int idx = blockIdx.x * 256 + threadIdx.x;     // (bt,h) over 4096*1024
  int h  = idx & (HEADS - 1);
  int bt = idx >> 10;
  int t  = bt & (LSEQ - 1);
  float draw = (float)zxb[(size_t)bt * PROJ + OFF_DT + h];
  float dt = (draw > 20.f) ? draw : log1pf(expf(draw));
  float Ah = -expf(A_log[h]);
  dta[idx] = dt * Ah;
  float4 w0 = *(const float4*)(conv_w + 8 * h);
  float4 w1 = *(const float4*)(conv_w + 8 * h + 4);
  float2 cb = *(const float2*)(conv_b + 2 * h);
  float acc0 = cb.x, acc1 = cb.y;
  float w0a[4] = {w0.x, w0.y, w0.z, w0.w};
  float w1a[4] = {w1.x, w1.y, w1.z, w1.w};
  #pragma unroll
  for (int k = 0; k < 4; ++k) {
    int tt = t - 3 + k;
    if (tt >= 0) {
      bf16x2 xv = *(const bf16x2*)(zxb + (size_t)(bt - 3 + k) * PROJ + OFF_X + 2 * h);
      acc0 = fmaf((float)xv[0], w0a[k], acc0);
      acc1 = fmaf((float)xv[1], w1a[k], acc1);
    }
  }
  float xs0 = siluf(acc0), xs1 = siluf(acc1);
  bf16x2 o; o[0] = (bf16_t)(dt * xs0); o[1] = (bf16_t)(dt * xs1);
  *(bf16x2*)(dtx + 2 * (size_t)idx) = o;
}

// ---------------- kg: per (b,c)  GT[j][i] = B_j . C_i  (fp32) + BTc[n][j] ----
__global__ __launch_bounds__(256) void kg_kernel(const bf16_t* __restrict__ zxb,
                                                 float* __restrict__ GT,
                                                 bf16_t* __restrict__ BTc) {
  __shared__ bf16_t lB[QCH * 128];
  __shared__ bf16_t lC[QCH * 128];
  int bc = blockIdx.x;              // b*NC + c
  int b = bc / NC, c = bc % NC;
  int t = threadIdx.x;
  size_t rowbase = ((size_t)b * LSEQ + c * QCH);
  #pragma unroll
  for (int p = 0; p < 4; ++p) {
    int row = p * 16 + (t >> 4);
    int eo  = (t & 15) * 8;
    gload_lds16(zxb + (rowbase + row) * PROJ + OFF_B + eo, lB + p * 2048 + t * 8);
    gload_lds16(zxb + (rowbase + row) * PROJ + OFF_C + eo, lC + p * 2048 + t * 8);
  }
  __syncthreads();
  int wv = t >> 6, lane = t & 63;
  int l15 = lane & 15, l4 = lane >> 4;
  f32x4 acc[4];
  #pragma unroll
  for (int i = 0; i < 4; ++i) acc[i] = (f32x4){0.f, 0.f, 0.f, 0.f};
  #pragma unroll
  for (int ks = 0; ks < 4; ++ks) {
    bf16x8 af = *(const bf16x8*)(lB + (16 * wv + l15) * 128 + ks * 32 + l4 * 8);
    #pragma unroll
    for (int it = 0; it < 4; ++it) {
      bf16x8 bq = *(const bf16x8*)(lC + (16 * it + l15) * 128 + ks * 32 + l4 * 8);
      acc[it] = __builtin_amdgcn_mfma_f32_16x16x32_bf16(af, bq, acc[it], 0, 0, 0);
    }
  }
  float* gout = GT + (size_t)bc * 4096;
  #pragma unroll
  for (int it = 0; it < 4; ++it) {
    int col = it * 16 + l15;
    #pragma unroll
    for (int r = 0; r < 4; ++r) {
      int j = 16 * wv + l4 * 4 + r;
      gout[j * 64 + col] = acc[it][r];
    }
  }
  bf16_t* bto = BTc + (size_t)bc * (128 * QCH);
  int n = t >> 1, j0 = (t & 1) * 32;
  #pragma unroll
  for (int jj = 0; jj < 32; ++jj)
    bto[n * QCH + j0 + jj] = lB[(j0 + jj) * 128 + n];
}

// ---------------- local: per (b,c,head) intra-chunk y + S,cd,D -------------
// block = 8 waves = 8 heads; lane = timestep i within chunk.
// GT staged to LDS masked (j<=i) and pair-packed: sp[(j>>1)*128 + i*2 + (j&1)].
// Inner loop: e = 2^min(ca2_i - ca2_j, 0) via raw v_exp; (ca2,v0,v1)_j via readlane.
__global__ __launch_bounds__(512) void local_kernel(const float* __restrict__ GT,
                                                    const float* __restrict__ dta,
                                                    const bf16_t* __restrict__ dtx,
                                                    float* __restrict__ y,
                                                    bf16_t* __restrict__ S,
                                                    bf16_t* __restrict__ cdb,
                                                    float* __restrict__ Dch) {
  __shared__ float sp[4096];         // masked pair-packed GT
  __shared__ float sy[QCH * 17];     // padded transpose buffer (64 t x 16 hp)
  int t = threadIdx.x;
  int wv = t >> 6, l = t & 63;
  int hg = blockIdx.x & 127;
  int c  = (blockIdx.x >> 7) & (NC - 1);
  int b  = blockIdx.x >> 12;
  int bc = b * NC + c;
  int h  = hg * 8 + wv;

  // load GT (8 floats/thread), mask upper triangle, pack pairs into LDS
  {
    const float* gsrc = GT + (size_t)bc * 4096 + t * 8;
    float4 a = *(const float4*)gsrc;
    float4 bq = *(const float4*)(gsrc + 4);
    int j  = t >> 3;            // row (64 elems per row, 8 rows per 64 threads)
    int i0 = (t & 7) * 8;       // col base
    float va[8] = {a.x, a.y, a.z, a.w, bq.x, bq.y, bq.z, bq.w};
    float* dstb = sp + (j >> 1) * 128 + (j & 1);
    #pragma unroll
    for (int k = 0; k < 8; ++k) {
      int i = i0 + k;
      dstb[i * 2] = (j <= i) ? va[k] : 0.f;
    }
  }

  int tIdx = c * QCH + l;
  size_t bt = (size_t)b * LSEQ + tIdx;
  float dtal = dta[bt * HEADS + h];
  bf16x2 vvb = *(const bf16x2*)(dtx + bt * D_INNER + 2 * h);
  float v0 = (float)vvb[0], v1 = (float)vvb[1];

  // inclusive prefix sum of dta over 64 lanes -> ca; work in log2 domain
  float ca = dtal;
  ca = dpp_add<0x111, 0xf>(ca);   // row_shr:1
  ca = dpp_add<0x112, 0xf>(ca);   // row_shr:2
  ca = dpp_add<0x114, 0xf>(ca);   // row_shr:4
  ca = dpp_add<0x118, 0xf>(ca);   // row_shr:8
  ca = dpp_add<0x142, 0xa>(ca);   // row_bcast:15 -> rows 1,3
  ca = dpp_add<0x143, 0xc>(ca);   // row_bcast:31 -> rows 2,3
  float ca2 = ca * LOG2E;

  float cdl = exp2_fast(ca2);
  cdb[((size_t)b * HEADS + h) * LSEQ + tIdx] = (bf16_t)cdl;
  float calast2 = rdlane(ca2, 63);
  float sc = exp2_fast(calast2 - ca2);
  bf16_t* srow = S + ((size_t)bc * D_INNER + 2 * h) * QCH + l;
  srow[0]   = (bf16_t)(sc * v0);
  srow[QCH] = (bf16_t)(sc * v1);
  if (l == 63) Dch[((size_t)b * HEADS + h) * NC + c] = cdl;
  __syncthreads();   // sp visible

  float y0 = 0.f, y1 = 0.f;
  const float* spb = sp + l * 2;
  #pragma unroll
  for (int j2 = 0; j2 < 32; ++j2) {
    float2 g2 = *(const float2*)(spb + j2 * 128);
    {
      float cj2 = rdlane(ca2, 2 * j2);
      float sv0 = rdlane(v0, 2 * j2);
      float sv1 = rdlane(v1, 2 * j2);
      float e = exp2_fast(fminf(ca2 - cj2, 0.f));
      float gg = e * g2.x;
      y0 = fmaf(gg, sv0, y0);
      y1 = fmaf(gg, sv1, y1);
    }
    {
      float cj2 = rdlane(ca2, 2 * j2 + 1);
      float sv0 = rdlane(v0, 2 * j2 + 1);
      float sv1 = rdlane(v1, 2 * j2 + 1);
      float e = exp2_fast(fminf(ca2 - cj2, 0.f));
      float gg = e * g2.y;
      y0 = fmaf(gg, sv0, y0);
      y1 = fmaf(gg, sv1, y1);
    }
  }
  sy[l * 17 + wv * 2]     = y0;
  sy[l * 17 + wv * 2 + 1] = y1;
  __syncthreads();
  int rowt = t >> 3, cc = (t & 7) * 2;
  float2 o = make_float2(sy[rowt * 17 + cc], sy[rowt * 17 + cc + 1]);
  *(float2*)(y + ((size_t)b * LSEQ + c * QCH + rowt) * D_INNER + hg * 16 + cc) = o;
}

// ---------------- state scan over chunks (in-place Hloc -> Hin, bf16) -------
__global__ __launch_bounds__(256) void state_kernel(bf16_t* __restrict__ Hst,
                                                    const float* __restrict__ Dch) {
  int g = blockIdx.x * 256 + threadIdx.x;   // (b, hp, nq) : 2*2048*32
  int nq = g & 31;
  int hp = (g >> 5) & (D_INNER - 1);
  int b  = g >> 16;
  int h  = hp >> 1;
  const float* Dp = Dch + ((size_t)b * HEADS + h) * NC;
  float4 cur = make_float4(0.f, 0.f, 0.f, 0.f);
  for (int c = 0; c < NC; ++c) {
    size_t idx = (((size_t)(b * NC + c) * D_INNER) + hp) * D_STATE + nq * 4;
    bf16x4 old = *(bf16x4*)(Hst + idx);
    bf16x4 w;
    w[0] = (bf16_t)cur.x; w[1] = (bf16_t)cur.y; w[2] = (bf16_t)cur.z; w[3] = (bf16_t)cur.w;
    *(bf16x4*)(Hst + idx) = w;
    float d = Dp[c];
    cur.x = fmaf(d, cur.x, (float)old[0]);
    cur.y = fmaf(d, cur.y, (float)old[1]);
    cur.z = fmaf(d, cur.z, (float)old[2]);
    cur.w = fmaf(d, cur.w, (float)old[3]);
  }
}

// ---------------- ycross: y += cd_i * (C_i . Hin[hp])  per (b,c) ------------
__global__ __launch_bounds__(256) void ycross_kernel(const bf16_t* __restrict__ zxb,
                                                     const bf16_t* __restrict__ Hst,
                                                     const bf16_t* __restrict__ cdb,
                                                     float* __restrict__ y) {
  __shared__ bf16_t lA[QCH * 32];
  __shared__ bf16_t lB[256 * 32];
  int nt = blockIdx.x & 7;
  int c  = (blockIdx.x >> 3) & (NC - 1);
  int b  = blockIdx.x >> 8;
  int bc = b * NC + c;
  int n0 = nt * 256;
  int t = threadIdx.x;
  int wv = t >> 6, lane = t & 63;
  int l15 = lane & 15, l4 = lane >> 4;
  size_t rowbase = (size_t)b * LSEQ + c * QCH;

  f32x4 acc[4][4];
  #pragma unroll
  for (int i = 0; i < 4; ++i)
    #pragma unroll
    for (int j = 0; j < 4; ++j) acc[i][j] = (f32x4){0.f, 0.f, 0.f, 0.f};

  int sr = t >> 2, sk = (t & 3) * 8;
  for (int ks = 0; ks < 4; ++ks) {
    int k0 = ks * 32;
    gload_lds16(zxb + (rowbase + sr) * PROJ + OFF_C + k0 + sk, lA + t * 8);
    #pragma unroll
    for (int p = 0; p < 4; ++p)
      gload_lds16(Hst + ((size_t)bc * D_INNER + n0 + p * 64 + sr) * D_STATE + k0 + sk,
                  lB + p * 2048 + t * 8);
    __syncthreads();
    #pragma unroll
    for (int i = 0; i < 4; ++i) {
      bf16x8 af = *(const bf16x8*)(lA + (i * 16 + l15) * 32 + l4 * 8);
      #pragma unroll
      for (int j = 0; j < 4; ++j) {
        bf16x8 bq = *(const bf16x8*)(lB + (wv * 64 + j * 16 + l15) * 32 + l4 * 8);
        acc[i][j] = __builtin_amdgcn_mfma_f32_16x16x32_bf16(af, bq, acc[i][j], 0, 0, 0);
      }
    }
    __syncthreads();
  }

  #pragma unroll
  for (int i = 0; i < 4; ++i) {
    int row = i * 16 + l4 * 4;
    #pragma unroll
    for (int j = 0; j < 4; ++j) {
      int col = n0 + wv * 64 + j * 16 + l15;   // hp
      int h = col >> 1;
      bf16x4 cd4 = *(const bf16x4*)(cdb + ((size_t)b * HEADS + h) * LSEQ + c * QCH + row);
      #pragma unroll
      for (int r = 0; r < 4; ++r) {
        size_t idx = (rowbase + row + r) * D_INNER + col;
        y[idx] += (float)cd4[r] * acc[i][j][r];
      }
    }
  }
}

// ---------------- gate: yg = y * silu(z) -> bf16 ----------------
__global__ __launch_bounds__(256) void gate_kernel(const float* __restrict__ y,
                                                   const bf16_t* __restrict__ zxb,
                                                   bf16_t* __restrict__ yg) {
  int tid = blockIdx.x * 256 + threadIdx.x;
  int row = tid >> 9;
  int c0  = (tid & 511) * 4;
  float4 yv = *(const float4*)(y + (size_t)row * D_INNER + c0);
  bf16x4 zv = *(const bf16x4*)(zxb + (size_t)row * PROJ + OFF_Z + c0);
  bf16x4 o;
  o[0] = (bf16_t)(yv.x * siluf((float)zv[0]));
  o[1] = (bf16_t)(yv.y * siluf((float)zv[1]));
  o[2] = (bf16_t)(yv.z * siluf((float)zv[2]));
  o[3] = (bf16_t)(yv.w * siluf((float)zv[3]));
  *(bf16x4*)(yg + (size_t)row * D_INNER + c0) = o;
}

// ---------------- launch ----------------
extern "C" void kernel_launch(void* const* d_in, const int* in_sizes, int n_in,
                              void* d_out, int out_size, void* d_ws, size_t ws_size,
                              hipStream_t stream) {
  const float* u      = (const float*)d_in[0];
  const float* W_in   = (const float*)d_in[1];
  const float* conv_w = (const float*)d_in[2];
  const float* conv_b = (const float*)d_in[3];
  const float* W_out  = (const float*)d_in[4];
  const float* ln_g   = (const float*)d_in[5];
  const float* ln_b   = (const float*)d_in[6];
  const float* A_log  = (const float*)d_in[7];
  float* out = (float*)d_out;

  char* ws = (char*)d_ws;
  bf16_t* W_inT  = (bf16_t*)ws;  ws += (size_t)PROJ * D_MODEL * 2;
  bf16_t* W_outT = (bf16_t*)ws;  ws += (size_t)D_MODEL * D_INNER * 2;
  bf16_t* xn     = (bf16_t*)ws;  ws += (size_t)NROW * D_MODEL * 2;
  bf16_t* zxb    = (bf16_t*)ws;  ws += (size_t)NROW * PROJ * 2;
  float*  dta    = (float*)ws;   ws += (size_t)NROW * HEADS * 4;
  bf16_t* dtx    = (bf16_t*)ws;  ws += (size_t)NROW * D_INNER * 2;
  float*  yy     = (float*)ws;   ws += (size_t)NROW * D_INNER * 4;
  bf16_t* yg     = (bf16_t*)ws;  ws += (size_t)NROW * D_INNER * 2;
  float*  GT     = (float*)ws;   ws += (size_t)BATCH * NC * 4096 * 4;
  bf16_t* BTc    = (bf16_t*)ws;  ws += (size_t)BATCH * NC * 128 * QCH * 2;
  bf16_t* S      = (bf16_t*)ws;  ws += (size_t)BATCH * NC * D_INNER * QCH * 2;
  bf16_t* cdb    = (bf16_t*)ws;  ws += (size_t)BATCH * HEADS * LSEQ * 2;
  float*  Dch    = (float*)ws;   ws += (size_t)BATCH * HEADS * NC * 4;
  bf16_t* Hst    = (bf16_t*)ws;  ws += (size_t)BATCH * NC * D_INNER * D_STATE * 2;

  dim3 tb(32, 8);
  transpose_kernel<<<dim3(PROJ / 32, D_MODEL / 32), tb, 0, stream>>>(W_in, W_inT, D_MODEL, PROJ);
  transpose_kernel<<<dim3(D_MODEL / 32, D_INNER / 32), tb, 0, stream>>>(W_out, W_outT, D_INNER, D_MODEL);
  ln_kernel<<<NROW, 256, 0, stream>>>(u, ln_g, ln_b, xn);
  gemm_bt<bf16_t><<<(NROW / 128) * (PROJ / 128), 256, 0, stream>>>(
      xn, W_inT, zxb, NROW, PROJ, D_MODEL, nullptr, (NROW / 128) * (PROJ / 128), 0, 0, 0);
  prep_kernel<<<NROW * HEADS / 256, 256, 0, stream>>>(zxb, conv_w, conv_b, A_log, dta, dtx);
  kg_kernel<<<BATCH * NC, 256, 0, stream>>>(zxb, GT, BTc);
  local_kernel<<<BATCH * NC * 128, 512, 0, stream>>>(GT, dta, dtx, yy, S, cdb, Dch);
  gemm_bt<bf16_t><<<BATCH * NC * 16, 256, 0, stream>>>(
      S, BTc, Hst, D_INNER, D_STATE, QCH, nullptr, 16,
      (long long)D_INNER * QCH, (long long)128 * QCH, (long long)D_INNER * D_STATE);
  state_kernel<<<BATCH * D_INNER * 32 / 256, 256, 0, stream>>>(Hst, Dch);
  ycross_kernel<<<BATCH * NC * 8, 256, 0, stream>>>(zxb, Hst, cdb, yy);
  gate_kernel<<<NROW * D_INNER / 4 / 256, 256, 0, stream>>>(yy, zxb, yg);
  gemm_bt<float><<<(NROW / 128) * (D_MODEL / 128), 256, 0, stream>>>(
      yg, W_outT, out, NROW, D_MODEL, D_INNER, u, (NROW / 128) * (D_MODEL / 128), 0, 0, 0);
}

// Round 6
// 397.744 us; speedup vs baseline: 2.6253x; 1.0363x over previous
//
#include <hip/hip_runtime.h>
#include <hip/hip_bf16.h>
#include <stdint.h>

// ---------------- types ----------------
typedef __bf16 bf16_t;
typedef bf16_t bf16x8 __attribute__((ext_vector_type(8)));
typedef bf16_t bf16x4 __attribute__((ext_vector_type(4)));
typedef bf16_t bf16x2 __attribute__((ext_vector_type(2)));
typedef float  f32x4  __attribute__((ext_vector_type(4)));

#define D_MODEL 1024
#define D_STATE 128
#define D_INNER 2048
#define HEADS   1024
#define PROJ    5376
#define LSEQ    2048
#define BATCH   2
#define NROW    (BATCH*LSEQ)   // 4096
#define QCH     64             // chunk length
#define NC      (LSEQ/QCH)     // 32 chunks per sequence

// offsets within a zxbcdt row
#define OFF_X   0
#define OFF_Z   2048
#define OFF_B   4096
#define OFF_C   4224
#define OFF_DT  4352

#define LOG2E 1.44269504088896340736f

typedef __attribute__((address_space(1))) void void_as1;
typedef __attribute__((address_space(3))) void void_as3;

__device__ __forceinline__ void gload_lds16(const void* g, void* l) {
  __builtin_amdgcn_global_load_lds((void_as1*)(uintptr_t)g,
                                   (void_as3*)(uint32_t)(uintptr_t)l,
                                   16, 0, 0);
}

__device__ __forceinline__ float siluf(float v) { return v / (1.f + expf(-v)); }

__device__ __forceinline__ float exp2_fast(float x) {
  float r;
  asm("v_exp_f32 %0, %1" : "=v"(r) : "v"(x));
  return r;
}

__device__ __forceinline__ float rdlane(float v, int l) {
  return __int_as_float(__builtin_amdgcn_readlane(__float_as_int(v), l));
}

template<int CTRL, int RM>
__device__ __forceinline__ float dpp_add(float x) {
  int s = __builtin_amdgcn_update_dpp(0, __float_as_int(x), CTRL, RM, 0xf, true);
  return x + __int_as_float(s);
}

// ---------------- transpose fp32 (R x C) -> bf16 (C x R) ----------------
__global__ __launch_bounds__(256) void transpose_kernel(const float* __restrict__ src,
                                                        bf16_t* __restrict__ dst,
                                                        int R, int C) {
  __shared__ float tile[32][33];
  int c0 = blockIdx.x * 32, r0 = blockIdx.y * 32;
  int tx = threadIdx.x, ty = threadIdx.y;
  #pragma unroll
  for (int i = ty; i < 32; i += 8)
    tile[i][tx] = src[(size_t)(r0 + i) * C + c0 + tx];
  __syncthreads();
  #pragma unroll
  for (int i = ty; i < 32; i += 8)
    dst[(size_t)(c0 + i) * R + r0 + tx] = (bf16_t)tile[tx][i];
}

// ---------------- layernorm -> bf16 ----------------
__global__ __launch_bounds__(256) void ln_kernel(const float* __restrict__ u,
                                                 const float* __restrict__ g,
                                                 const float* __restrict__ bb,
                                                 bf16_t* __restrict__ xn) {
  int row = blockIdx.x;
  int t = threadIdx.x;
  float4 v = ((const float4*)(u + (size_t)row * D_MODEL))[t];
  float s  = v.x + v.y + v.z + v.w;
  float s2 = v.x*v.x + v.y*v.y + v.z*v.z + v.w*v.w;
  #pragma unroll
  for (int m = 1; m < 64; m <<= 1) { s += __shfl_xor(s, m, 64); s2 += __shfl_xor(s2, m, 64); }
  __shared__ float ws[8];
  int wv = t >> 6, lane = t & 63;
  if (lane == 0) { ws[wv] = s; ws[4 + wv] = s2; }
  __syncthreads();
  s  = ws[0] + ws[1] + ws[2] + ws[3];
  s2 = ws[4] + ws[5] + ws[6] + ws[7];
  float mean = s * (1.f / D_MODEL);
  float var  = s2 * (1.f / D_MODEL) - mean * mean;
  float rstd = rsqrtf(var + 1e-5f);
  float4 gv = ((const float4*)g)[t];
  float4 bv = ((const float4*)bb)[t];
  bf16x4 o;
  o[0] = (bf16_t)((v.x - mean) * rstd * gv.x + bv.x);
  o[1] = (bf16_t)((v.y - mean) * rstd * gv.y + bv.y);
  o[2] = (bf16_t)((v.z - mean) * rstd * gv.z + bv.z);
  o[3] = (bf16_t)((v.w - mean) * rstd * gv.w + bv.w);
  *(bf16x4*)(xn + (size_t)row * D_MODEL + t * 4) = o;
}

// ============ GEMM1: 8-phase 128x256 tile, K=1024, C bf16 ============
// A[4096][1024] bf16, BT[5376][1024] bf16, C[4096][5376] bf16.
// 512 thr = 8 waves (wm 0..1, wn 0..3), per-wave out 64x64.
// LDS per buf (48KB): A-half0(8K) A-half1(8K) B-half0(16K) B-half1(16K); 2 bufs.
// Swizzle: 16B slot s at row r holds global col-group s^(r&7)  (involution).
#define G1_NT 16
#define MFMA_BF16(a,b,c) __builtin_amdgcn_mfma_f32_16x16x32_bf16(a,b,c,0,0,0)

__global__ __launch_bounds__(512, 2) void gemm1_8ph(const bf16_t* __restrict__ A,
                                                    const bf16_t* __restrict__ BT,
                                                    bf16_t* __restrict__ C) {
  __shared__ __align__(16) char smem[98304];
  int bid = blockIdx.x;
  int s8  = (bid & 7) * 84 + (bid >> 3);      // XCD swizzle (672 = 8*84)
  int tm = s8 / 21, tn = s8 % 21;
  int m0 = tm << 7, n0 = tn << 8;
  int tid = threadIdx.x;
  int wid = tid >> 6, lane = tid & 63;
  int wm = wid >> 2, wn = wid & 3;
  int l15 = lane & 15, l4 = lane >> 4;

  const bf16_t* Ab = A  + (size_t)m0 * 1024;
  const bf16_t* Bb = BT + (size_t)n0 * 1024;
  int rowA = tid >> 3;
  int gcol = ((tid & 7) ^ (rowA & 7)) * 8;    // pre-swizzled global col (bf16)

  // ds_read byte offsets (per-lane constant)
  int sw0 = (l4 * 16) ^ ((l15 & 7) << 4);
  int sw1 = sw0 ^ 64;
  int ar0 = (wm * 32 + l15) * 128;            // A row byte base, mf=0
  int ar1 = ar0 + 2048;                       // mf=1 (+16 rows)
  int br0 = (wn * 32 + l15) * 128;
  int br1 = br0 + 2048;

  f32x4 acc[2][2][2][2];
  #pragma unroll
  for (int a = 0; a < 2; ++a)
    #pragma unroll
    for (int b = 0; b < 2; ++b)
      #pragma unroll
      for (int c = 0; c < 2; ++c)
        #pragma unroll
        for (int d = 0; d < 2; ++d) acc[a][b][c][d] = (f32x4){0.f,0.f,0.f,0.f};

#define STAGE_A(half, t) do { \
    const bf16_t* _s = Ab + ((size_t)((half)*64 + rowA) * 1024) + (t)*64 + gcol; \
    gload_lds16(_s, smem + ((t)&1)*49152 + (half)*8192 + tid*16); \
  } while(0)
#define STAGE_B(half, t) do { \
    const bf16_t* _s = Bb + ((size_t)((half)*128 + rowA) * 1024) + (t)*64 + gcol; \
    char* _d = smem + ((t)&1)*49152 + 16384 + (half)*16384 + tid*16; \
    gload_lds16(_s, _d); \
    gload_lds16(_s + 64*1024, _d + 8192); \
  } while(0)

#define PHASE(qm, qn, dd, STMT_STAGE, STMT_VM) do { \
    const char* pa = smem + (dd)*49152 + (qm)*8192; \
    const char* pb = smem + (dd)*49152 + 16384 + (qn)*16384; \
    bf16x8 a00 = *(const bf16x8*)(pa + ar0 + sw0); \
    bf16x8 a01 = *(const bf16x8*)(pa + ar0 + sw1); \
    bf16x8 a10 = *(const bf16x8*)(pa + ar1 + sw0); \
    bf16x8 a11 = *(const bf16x8*)(pa + ar1 + sw1); \
    bf16x8 b00 = *(const bf16x8*)(pb + br0 + sw0); \
    bf16x8 b01 = *(const bf16x8*)(pb + br0 + sw1); \
    bf16x8 b10 = *(const bf16x8*)(pb + br1 + sw0); \
    bf16x8 b11 = *(const bf16x8*)(pb + br1 + sw1); \
    STMT_STAGE; \
    __builtin_amdgcn_s_barrier(); \
    asm volatile("s_waitcnt lgkmcnt(0)" ::: "memory"); \
    __builtin_amdgcn_sched_barrier(0); \
    __builtin_amdgcn_s_setprio(1); \
    acc[qm][qn][0][0] = MFMA_BF16(a00, b00, acc[qm][qn][0][0]); \
    acc[qm][qn][0][1] = MFMA_BF16(a00, b10, acc[qm][qn][0][1]); \
    acc[qm][qn][1][0] = MFMA_BF16(a10, b00, acc[qm][qn][1][0]); \
    acc[qm][qn][1][1] = MFMA_BF16(a10, b10, acc[qm][qn][1][1]); \
    acc[qm][qn][0][0] = MFMA_BF16(a01, b01, acc[qm][qn][0][0]); \
    acc[qm][qn][0][1] = MFMA_BF16(a01, b11, acc[qm][qn][0][1]); \
    acc[qm][qn][1][0] = MFMA_BF16(a11, b01, acc[qm][qn][1][0]); \
    acc[qm][qn][1][1] = MFMA_BF16(a11, b11, acc[qm][qn][1][1]); \
    __builtin_amdgcn_s_setprio(0); \
    __builtin_amdgcn_sched_barrier(0); \
    STMT_VM; \
    __builtin_amdgcn_s_barrier(); \
  } while(0)

  // prologue: tile0 complete + A0/B0 of tile1 ; keep 3 loads in flight
  STAGE_A(0, 0); STAGE_B(0, 0); STAGE_B(1, 0); STAGE_A(1, 0);
  STAGE_A(0, 1); STAGE_B(0, 1);
  asm volatile("s_waitcnt vmcnt(3)" ::: "memory");
  __builtin_amdgcn_s_barrier();

  for (int t = 0; t < G1_NT; ++t) {
    int dd = t & 1;
    PHASE(0, 0, dd, { if (t + 1 < G1_NT) STAGE_B(1, t + 1); }, {});
    PHASE(0, 1, dd, { if (t + 1 < G1_NT) STAGE_A(1, t + 1); }, {});
    PHASE(1, 0, dd, { if (t + 2 < G1_NT) STAGE_A(0, t + 2); }, {});
    PHASE(1, 1, dd, { if (t + 2 < G1_NT) STAGE_B(0, t + 2); },
          { if (t <= G1_NT - 3) asm volatile("s_waitcnt vmcnt(3)" ::: "memory");
            else                asm volatile("s_waitcnt vmcnt(0)" ::: "memory"); });
  }

  // epilogue
  #pragma unroll
  for (int qm = 0; qm < 2; ++qm)
    #pragma unroll
    for (int qn = 0; qn < 2; ++qn)
      #pragma unroll
      for (int mf = 0; mf < 2; ++mf)
        #pragma unroll
        for (int nf = 0; nf < 2; ++nf) {
          int row = m0 + qm * 64 + wm * 32 + mf * 16 + l4 * 4;
          int col = n0 + qn * 128 + wn * 32 + nf * 16 + l15;
          f32x4 v = acc[qm][qn][mf][nf];
          #pragma unroll
          for (int r = 0; r < 4; ++r)
            C[(size_t)(row + r) * PROJ + col] = (bf16_t)v[r];
        }
#undef STAGE_A
#undef STAGE_B
#undef PHASE
}

// ---------------- GEMM  C[M,N] = A[M,K] * BT[N,K]^T  (min-2-phase dbuf) ------
template<typename CT>
__global__ __launch_bounds__(256) void gemm_bt(const bf16_t* __restrict__ A,
                                               const bf16_t* __restrict__ BT,
                                               CT* __restrict__ C,
                                               int M, int N, int K,
                                               const float* __restrict__ resid,
                                               int tilesPerBatch,
                                               long long sA, long long sB, long long sC) {
  __shared__ __align__(16) bf16_t lA[2][128 * 32];
  __shared__ __align__(16) bf16_t lB[2][128 * 32];
  int bat = blockIdx.x / tilesPerBatch;
  int tl  = blockIdx.x % tilesPerBatch;
  A += (size_t)bat * sA; BT += (size_t)bat * sB; C += (size_t)bat * sC;
  int ntile = N >> 7;
  int tm = tl / ntile, tn = tl % ntile;
  int m0 = tm << 7, n0 = tn << 7;
  int t = threadIdx.x;
  int wv = t >> 6, lane = t & 63;
  int wm = (wv >> 1) << 6, wn = (wv & 1) << 6;
  int l15 = lane & 15, l4 = lane >> 4;

  f32x4 acc[4][4];
  #pragma unroll
  for (int i = 0; i < 4; ++i)
    #pragma unroll
    for (int j = 0; j < 4; ++j) acc[i][j] = (f32x4){0.f, 0.f, 0.f, 0.f};

  int sr = t >> 2;
  int sk = (t & 3) * 8;
  const bf16_t* ga  = A  + (size_t)(m0 + sr) * K + sk;
  const bf16_t* ga2 = ga + (size_t)64 * K;
  const bf16_t* gb  = BT + (size_t)(n0 + sr) * K + sk;
  const bf16_t* gb2 = gb + (size_t)64 * K;

  int raOff = (wm + l15) * 64 + l4 * 16;   // byte offsets
  int rbOff = (wn + l15) * 64 + l4 * 16;

#define ST2(dd) do { \
    char* _da = (char*)lA + (dd) * 8192 + t * 16; \
    char* _db = (char*)lB + (dd) * 8192 + t * 16; \
    gload_lds16(ga, _da);  gload_lds16(ga2, _da + 4096); \
    gload_lds16(gb, _db);  gload_lds16(gb2, _db + 4096); \
    ga += 32; ga2 += 32; gb += 32; gb2 += 32; \
  } while(0)

  // prologue
  ST2(0);
  asm volatile("s_waitcnt vmcnt(0)" ::: "memory");
  __builtin_amdgcn_s_barrier();

  int cur = 0;
  for (int k0 = 0; k0 < K; k0 += 32) {
    if (k0 + 32 < K) ST2(cur ^ 1);
    bf16x8 af[4], bq[4];
    #pragma unroll
    for (int f = 0; f < 4; ++f) {
      af[f] = *(const bf16x8*)((const char*)lA + cur * 8192 + raOff + f * 1024);
      bq[f] = *(const bf16x8*)((const char*)lB + cur * 8192 + rbOff + f * 1024);
    }
    #pragma unroll
    for (int i = 0; i < 4; ++i)
      #pragma unroll
      for (int j = 0; j < 4; ++j)
        acc[i][j] = MFMA_BF16(af[i], bq[j], acc[i][j]);
    asm volatile("s_waitcnt lgkmcnt(0)" ::: "memory");
    asm volatile("s_waitcnt vmcnt(0)" ::: "memory");
    __builtin_amdgcn_s_barrier();
    cur ^= 1;
  }
#undef ST2

  #pragma unroll
  for (int i = 0; i < 4; ++i) {
    int row = m0 + wm + i * 16 + l4 * 4;
    #pragma unroll
    for (int j = 0; j < 4; ++j) {
      int col = n0 + wn + j * 16 + l15;
      #pragma unroll
      for (int r = 0; r < 4; ++r) {
        size_t idx = (size_t)(row + r) * N + col;
        float v = acc[i][j][r];
        if (resid) v += resid[idx];
        C[idx] = (CT)v;
      }
    }
  }
}

// ---------------- prep: softplus(dt) -> dta, conv4+silu -> dtx (bf16) --------
__global__ __launch_bounds__(256) void prep_kernel(const bf16_t* __restrict__ zxb,
                                                   const float* __restrict__ conv_w,
                                                   const float* __restrict__ conv_b,
                                                   const float* __restrict__ A_log,
                                                   float* __restrict__ dta,
                                                   bf16_t* __restrict__ dtx) {
  int idx = blockIdx.x * 256 + threadIdx.x;     // (bt,h) over 4096*1024
  int h  = idx & (HEADS - 1);
  int bt = idx >> 10;
  int t  = bt & (LSEQ - 1);
  float draw = (float)zxb[(size_t)bt * PROJ + OFF_DT + h];
  float dt = (draw > 20.f) ? draw : log1pf(expf(draw));
  float Ah = -expf(A_log[h]);
  dta[idx] = dt * Ah;
  float4 w0 = *(const float4*)(conv_w + 8 * h);
  float4 w1 = *(const float4*)(conv_w + 8 * h + 4);
  float2 cb = *(const float2*)(conv_b + 2 * h);
  float acc0 = cb.x, acc1 = cb.y;
  float w0a[4] = {w0.x, w0.y, w0.z, w0.w};
  float w1a[4] = {w1.x, w1.y, w1.z, w1.w};
  #pragma unroll
  for (int k = 0; k < 4; ++k) {
    int tt = t - 3 + k;
    if (tt >= 0) {
      bf16x2 xv = *(const bf16x2*)(zxb + (size_t)(bt - 3 + k) * PROJ + OFF_X + 2 * h);
      acc0 = fmaf((float)xv[0], w0a[k], acc0);
      acc1 = fmaf((float)xv[1], w1a[k], acc1);
    }
  }
  float xs0 = siluf(acc0), xs1 = siluf(acc1);
  bf16x2 o; o[0] = (bf16_t)(dt * xs0); o[1] = (bf16_t)(dt * xs1);
  *(bf16x2*)(dtx + 2 * (size_t)idx) = o;
}

// ---------------- kg: per (b,c)  GT[j][i] = B_j . C_i  (fp32) + BTc[n][j] ----
__global__ __launch_bounds__(256) void kg_kernel(const bf16_t* __restrict__ zxb,
                                                 float* __restrict__ GT,
                                                 bf16_t* __restrict__ BTc) {
  __shared__ bf16_t lB[QCH * 128];
  __shared__ bf16_t lC[QCH * 128];
  int bc = blockIdx.x;              // b*NC + c
  int b = bc / NC, c = bc % NC;
  int t = threadIdx.x;
  size_t rowbase = ((size_t)b * LSEQ + c * QCH);
  #pragma unroll
  for (int p = 0; p < 4; ++p) {
    int row = p * 16 + (t >> 4);
    int eo  = (t & 15) * 8;
    gload_lds16(zxb + (rowbase + row) * PROJ + OFF_B + eo, lB + p * 2048 + t * 8);
    gload_lds16(zxb + (rowbase + row) * PROJ + OFF_C + eo, lC + p * 2048 + t * 8);
  }
  __syncthreads();
  int wv = t >> 6, lane = t & 63;
  int l15 = lane & 15, l4 = lane >> 4;
  f32x4 acc[4];
  #pragma unroll
  for (int i = 0; i < 4; ++i) acc[i] = (f32x4){0.f, 0.f, 0.f, 0.f};
  #pragma unroll
  for (int ks = 0; ks < 4; ++ks) {
    bf16x8 af = *(const bf16x8*)(lB + (16 * wv + l15) * 128 + ks * 32 + l4 * 8);
    #pragma unroll
    for (int it = 0; it < 4; ++it) {
      bf16x8 bq = *(const bf16x8*)(lC + (16 * it + l15) * 128 + ks * 32 + l4 * 8);
      acc[it] = __builtin_amdgcn_mfma_f32_16x16x32_bf16(af, bq, acc[it], 0, 0, 0);
    }
  }
  float* gout = GT + (size_t)bc * 4096;
  #pragma unroll
  for (int it = 0; it < 4; ++it) {
    int col = it * 16 + l15;
    #pragma unroll
    for (int r = 0; r < 4; ++r) {
      int j = 16 * wv + l4 * 4 + r;
      gout[j * 64 + col] = acc[it][r];
    }
  }
  bf16_t* bto = BTc + (size_t)bc * (128 * QCH);
  int n = t >> 1, j0 = (t & 1) * 32;
  #pragma unroll
  for (int jj = 0; jj < 32; ++jj)
    bto[n * QCH + j0 + jj] = lB[(j0 + jj) * 128 + n];
}

// ---------------- local: per (b,c,head) intra-chunk y + S,cd,D -------------
__global__ __launch_bounds__(512) void local_kernel(const float* __restrict__ GT,
                                                    const float* __restrict__ dta,
                                                    const bf16_t* __restrict__ dtx,
                                                    float* __restrict__ y,
                                                    bf16_t* __restrict__ S,
                                                    bf16_t* __restrict__ cdb,
                                                    float* __restrict__ Dch) {
  __shared__ float sp[4096];         // masked pair-packed GT
  __shared__ float sy[QCH * 17];     // padded transpose buffer (64 t x 16 hp)
  int t = threadIdx.x;
  int wv = t >> 6, l = t & 63;
  int hg = blockIdx.x & 127;
  int c  = (blockIdx.x >> 7) & (NC - 1);
  int b  = blockIdx.x >> 12;
  int bc = b * NC + c;
  int h  = hg * 8 + wv;

  {
    const float* gsrc = GT + (size_t)bc * 4096 + t * 8;
    float4 a = *(const float4*)gsrc;
    float4 bq = *(const float4*)(gsrc + 4);
    int j  = t >> 3;
    int i0 = (t & 7) * 8;
    float va[8] = {a.x, a.y, a.z, a.w, bq.x, bq.y, bq.z, bq.w};
    float* dstb = sp + (j >> 1) * 128 + (j & 1);
    #pragma unroll
    for (int k = 0; k < 8; ++k) {
      int i = i0 + k;
      dstb[i * 2] = (j <= i) ? va[k] : 0.f;
    }
  }

  int tIdx = c * QCH + l;
  size_t bt = (size_t)b * LSEQ + tIdx;
  float dtal = dta[bt * HEADS + h];
  bf16x2 vvb = *(const bf16x2*)(dtx + bt * D_INNER + 2 * h);
  float v0 = (float)vvb[0], v1 = (float)vvb[1];

  float ca = dtal;
  ca = dpp_add<0x111, 0xf>(ca);
  ca = dpp_add<0x112, 0xf>(ca);
  ca = dpp_add<0x114, 0xf>(ca);
  ca = dpp_add<0x118, 0xf>(ca);
  ca = dpp_add<0x142, 0xa>(ca);
  ca = dpp_add<0x143, 0xc>(ca);
  float ca2 = ca * LOG2E;

  float cdl = exp2_fast(ca2);
  cdb[((size_t)b * HEADS + h) * LSEQ + tIdx] = (bf16_t)cdl;
  float calast2 = rdlane(ca2, 63);
  float sc = exp2_fast(calast2 - ca2);
  bf16_t* srow = S + ((size_t)bc * D_INNER + 2 * h) * QCH + l;
  srow[0]   = (bf16_t)(sc * v0);
  srow[QCH] = (bf16_t)(sc * v1);
  if (l == 63) Dch[((size_t)b * HEADS + h) * NC + c] = cdl;
  __syncthreads();

  float y0 = 0.f, y1 = 0.f;
  const float* spb = sp + l * 2;
  #pragma unroll
  for (int j2 = 0; j2 < 32; ++j2) {
    float2 g2 = *(const float2*)(spb + j2 * 128);
    {
      float cj2 = rdlane(ca2, 2 * j2);
      float sv0 = rdlane(v0, 2 * j2);
      float sv1 = rdlane(v1, 2 * j2);
      float e = exp2_fast(fminf(ca2 - cj2, 0.f));
      float gg = e * g2.x;
      y0 = fmaf(gg, sv0, y0);
      y1 = fmaf(gg, sv1, y1);
    }
    {
      float cj2 = rdlane(ca2, 2 * j2 + 1);
      float sv0 = rdlane(v0, 2 * j2 + 1);
      float sv1 = rdlane(v1, 2 * j2 + 1);
      float e = exp2_fast(fminf(ca2 - cj2, 0.f));
      float gg = e * g2.y;
      y0 = fmaf(gg, sv0, y0);
      y1 = fmaf(gg, sv1, y1);
    }
  }
  sy[l * 17 + wv * 2]     = y0;
  sy[l * 17 + wv * 2 + 1] = y1;
  __syncthreads();
  int rowt = t >> 3, cc = (t & 7) * 2;
  float2 o = make_float2(sy[rowt * 17 + cc], sy[rowt * 17 + cc + 1]);
  *(float2*)(y + ((size_t)b * LSEQ + c * QCH + rowt) * D_INNER + hg * 16 + cc) = o;
}

// ---------------- state scan over chunks (in-place Hloc -> Hin, bf16) -------
__global__ __launch_bounds__(256) void state_kernel(bf16_t* __restrict__ Hst,
                                                    const float* __restrict__ Dch) {
  int g = blockIdx.x * 256 + threadIdx.x;   // (b, hp, nq) : 2*2048*32
  int nq = g & 31;
  int hp = (g >> 5) & (D_INNER - 1);
  int b  = g >> 16;
  int h  = hp >> 1;
  const float* Dp = Dch + ((size_t)b * HEADS + h) * NC;
  float4 cur = make_float4(0.f, 0.f, 0.f, 0.f);
  for (int c = 0; c < NC; ++c) {
    size_t idx = (((size_t)(b * NC + c) * D_INNER) + hp) * D_STATE + nq * 4;
    bf16x4 old = *(bf16x4*)(Hst + idx);
    bf16x4 w;
    w[0] = (bf16_t)cur.x; w[1] = (bf16_t)cur.y; w[2] = (bf16_t)cur.z; w[3] = (bf16_t)cur.w;
    *(bf16x4*)(Hst + idx) = w;
    float d = Dp[c];
    cur.x = fmaf(d, cur.x, (float)old[0]);
    cur.y = fmaf(d, cur.y, (float)old[1]);
    cur.z = fmaf(d, cur.z, (float)old[2]);
    cur.w = fmaf(d, cur.w, (float)old[3]);
  }
}

// ---------------- ycross: y += cd_i * (C_i . Hin[hp])  per (b,c) ------------
__global__ __launch_bounds__(256) void ycross_kernel(const bf16_t* __restrict__ zxb,
                                                     const bf16_t* __restrict__ Hst,
                                                     const bf16_t* __restrict__ cdb,
                                                     float* __restrict__ y) {
  __shared__ bf16_t lA[QCH * 32];
  __shared__ bf16_t lB[256 * 32];
  int nt = blockIdx.x & 7;
  int c  = (blockIdx.x >> 3) & (NC - 1);
  int b  = blockIdx.x >> 8;
  int bc = b * NC + c;
  int n0 = nt * 256;
  int t = threadIdx.x;
  int wv = t >> 6, lane = t & 63;
  int l15 = lane & 15, l4 = lane >> 4;
  size_t rowbase = (size_t)b * LSEQ + c * QCH;

  f32x4 acc[4][4];
  #pragma unroll
  for (int i = 0; i < 4; ++i)
    #pragma unroll
    for (int j = 0; j < 4; ++j) acc[i][j] = (f32x4){0.f, 0.f, 0.f, 0.f};

  int sr = t >> 2, sk = (t & 3) * 8;
  for (int ks = 0; ks < 4; ++ks) {
    int k0 = ks * 32;
    gload_lds16(zxb + (rowbase + sr) * PROJ + OFF_C + k0 + sk, lA + t * 8);
    #pragma unroll
    for (int p = 0; p < 4; ++p)
      gload_lds16(Hst + ((size_t)bc * D_INNER + n0 + p * 64 + sr) * D_STATE + k0 + sk,
                  lB + p * 2048 + t * 8);
    __syncthreads();
    #pragma unroll
    for (int i = 0; i < 4; ++i) {
      bf16x8 af = *(const bf16x8*)(lA + (i * 16 + l15) * 32 + l4 * 8);
      #pragma unroll
      for (int j = 0; j < 4; ++j) {
        bf16x8 bq = *(const bf16x8*)(lB + (wv * 64 + j * 16 + l15) * 32 + l4 * 8);
        acc[i][j] = __builtin_amdgcn_mfma_f32_16x16x32_bf16(af, bq, acc[i][j], 0, 0, 0);
      }
    }
    __syncthreads();
  }

  #pragma unroll
  for (int i = 0; i < 4; ++i) {
    int row = i * 16 + l4 * 4;
    #pragma unroll
    for (int j = 0; j < 4; ++j) {
      int col = n0 + wv * 64 + j * 16 + l15;   // hp
      int h = col >> 1;
      bf16x4 cd4 = *(const bf16x4*)(cdb + ((size_t)b * HEADS + h) * LSEQ + c * QCH + row);
      #pragma unroll
      for (int r = 0; r < 4; ++r) {
        size_t idx = (rowbase + row + r) * D_INNER + col;
        y[idx] += (float)cd4[r] * acc[i][j][r];
      }
    }
  }
}

// ---------------- gate: yg = y * silu(z) -> bf16 ----------------
__global__ __launch_bounds__(256) void gate_kernel(const float* __restrict__ y,
                                                   const bf16_t* __restrict__ zxb,
                                                   bf16_t* __restrict__ yg) {
  int tid = blockIdx.x * 256 + threadIdx.x;
  int row = tid >> 9;
  int c0  = (tid & 511) * 4;
  float4 yv = *(const float4*)(y + (size_t)row * D_INNER + c0);
  bf16x4 zv = *(const bf16x4*)(zxb + (size_t)row * PROJ + OFF_Z + c0);
  bf16x4 o;
  o[0] = (bf16_t)(yv.x * siluf((float)zv[0]));
  o[1] = (bf16_t)(yv.y * siluf((float)zv[1]));
  o[2] = (bf16_t)(yv.z * siluf((float)zv[2]));
  o[3] = (bf16_t)(yv.w * siluf((float)zv[3]));
  *(bf16x4*)(yg + (size_t)row * D_INNER + c0) = o;
}

// ---------------- launch ----------------
extern "C" void kernel_launch(void* const* d_in, const int* in_sizes, int n_in,
                              void* d_out, int out_size, void* d_ws, size_t ws_size,
                              hipStream_t stream) {
  const float* u      = (const float*)d_in[0];
  const float* W_in   = (const float*)d_in[1];
  const float* conv_w = (const float*)d_in[2];
  const float* conv_b = (const float*)d_in[3];
  const float* W_out  = (const float*)d_in[4];
  const float* ln_g   = (const float*)d_in[5];
  const float* ln_b   = (const float*)d_in[6];
  const float* A_log  = (const float*)d_in[7];
  float* out = (float*)d_out;

  char* ws = (char*)d_ws;
  bf16_t* W_inT  = (bf16_t*)ws;  ws += (size_t)PROJ * D_MODEL * 2;
  bf16_t* W_outT = (bf16_t*)ws;  ws += (size_t)D_MODEL * D_INNER * 2;
  bf16_t* xn     = (bf16_t*)ws;  ws += (size_t)NROW * D_MODEL * 2;
  bf16_t* zxb    = (bf16_t*)ws;  ws += (size_t)NROW * PROJ * 2;
  float*  dta    = (float*)ws;   ws += (size_t)NROW * HEADS * 4;
  bf16_t* dtx    = (bf16_t*)ws;  ws += (size_t)NROW * D_INNER * 2;
  float*  yy     = (float*)ws;   ws += (size_t)NROW * D_INNER * 4;
  bf16_t* yg     = (bf16_t*)ws;  ws += (size_t)NROW * D_INNER * 2;
  float*  GT     = (float*)ws;   ws += (size_t)BATCH * NC * 4096 * 4;
  bf16_t* BTc    = (bf16_t*)ws;  ws += (size_t)BATCH * NC * 128 * QCH * 2;
  bf16_t* S      = (bf16_t*)ws;  ws += (size_t)BATCH * NC * D_INNER * QCH * 2;
  bf16_t* cdb    = (bf16_t*)ws;  ws += (size_t)BATCH * HEADS * LSEQ * 2;
  float*  Dch    = (float*)ws;   ws += (size_t)BATCH * HEADS * NC * 4;
  bf16_t* Hst    = (bf16_t*)ws;  ws += (size_t)BATCH * NC * D_INNER * D_STATE * 2;

  dim3 tb(32, 8);
  transpose_kernel<<<dim3(PROJ / 32, D_MODEL / 32), tb, 0, stream>>>(W_in, W_inT, D_MODEL, PROJ);
  transpose_kernel<<<dim3(D_MODEL / 32, D_INNER / 32), tb, 0, stream>>>(W_out, W_outT, D_INNER, D_MODEL);
  ln_kernel<<<NROW, 256, 0, stream>>>(u, ln_g, ln_b, xn);
  gemm1_8ph<<<(NROW / 128) * (PROJ / 256), 512, 0, stream>>>(xn, W_inT, zxb);
  prep_kernel<<<NROW * HEADS / 256, 256, 0, stream>>>(zxb, conv_w, conv_b, A_log, dta, dtx);
  kg_kernel<<<BATCH * NC, 256, 0, stream>>>(zxb, GT, BTc);
  local_kernel<<<BATCH * NC * 128, 512, 0, stream>>>(GT, dta, dtx, yy, S, cdb, Dch);
  gemm_bt<bf16_t><<<BATCH * NC * 16, 256, 0, stream>>>(
      S, BTc, Hst, D_INNER, D_STATE, QCH, nullptr, 16,
      (long long)D_INNER * QCH, (long long)128 * QCH, (long long)D_INNER * D_STATE);
  state_kernel<<<BATCH * D_INNER * 32 / 256, 256, 0, stream>>>(Hst, Dch);
  ycross_kernel<<<BATCH * NC * 8, 256, 0, stream>>>(zxb, Hst, cdb, yy);
  gate_kernel<<<NROW * D_INNER / 4 / 256, 256, 0, stream>>>(yy, zxb, yg);
  gemm_bt<float><<<(NROW / 128) * (D_MODEL / 128), 256, 0, stream>>>(
      yg, W_outT, out, NROW, D_MODEL, D_INNER, u, (NROW / 128) * (D_MODEL / 128), 0, 0, 0);
}